// Round 18
// baseline (228.562 us; speedup 1.0000x reference)
//
#include <hip/hip_runtime.h>
#include <hip/hip_bf16.h>
#include <hip/hip_fp16.h>

// Problem constants
#define B_   2048
#define NN   128    // NMAX
#define MM   64     // HN
#define HD_  128
#define IND  18
#define FD_  16

typedef unsigned int u32;
typedef _Float16 h2_t __attribute__((ext_vector_type(2)));
typedef __attribute__((ext_vector_type(8))) short bf16x8;
typedef __attribute__((ext_vector_type(4))) float f32x4;

__device__ __forceinline__ float fdot2f(u32 a, u32 b, float c) {
#if defined(__has_builtin)
#if __has_builtin(__builtin_amdgcn_fdot2)
  return __builtin_amdgcn_fdot2(__builtin_bit_cast(h2_t, a),
                                __builtin_bit_cast(h2_t, b), c, false);
#else
  h2_t x = __builtin_bit_cast(h2_t, a), y = __builtin_bit_cast(h2_t, b);
  return c + (float)x[0] * (float)y[0] + (float)x[1] * (float)y[1];
#endif
#else
  h2_t x = __builtin_bit_cast(h2_t, a), y = __builtin_bit_cast(h2_t, b);
  return c + (float)x[0] * (float)y[0] + (float)x[1] * (float)y[1];
#endif
}

__device__ __forceinline__ u32 pk2(float a, float b) {
#if defined(__has_builtin)
#if __has_builtin(__builtin_amdgcn_cvt_pkrtz)
  return __builtin_bit_cast(u32, __builtin_amdgcn_cvt_pkrtz(a, b));
#else
  __half ha = __float2half_rn(a), hb = __float2half_rn(b);
  return (u32)__half_as_ushort(ha) | ((u32)__half_as_ushort(hb) << 16);
#endif
#else
  __half ha = __float2half_rn(a), hb = __float2half_rn(b);
  return (u32)__half_as_ushort(ha) | ((u32)__half_as_ushort(hb) << 16);
#endif
}

__device__ __forceinline__ float rcpf_(float x) {
#if defined(__has_builtin)
#if __has_builtin(__builtin_amdgcn_rcpf)
  return __builtin_amdgcn_rcpf(x);
#else
  return 1.0f / x;
#endif
#else
  return 1.0f / x;
#endif
}

__device__ __forceinline__ float h_lo(u32 d) {
  return __half2float(__ushort_as_half((unsigned short)(d & 0xffffu)));
}
__device__ __forceinline__ float h_hi(u32 d) {
  return __half2float(__ushort_as_half((unsigned short)(d >> 16)));
}

__device__ __forceinline__ float bf2f(unsigned short u) {
  union { float f; u32 i; } z; z.i = ((u32)u) << 16; return z.f;
}
__device__ __forceinline__ unsigned short f2bf(float f) {
  union { float fv; u32 u; } z; z.fv = f;
  u32 lsb = (z.u >> 16) & 1u;
  return (unsigned short)((z.u + 0x7fffu + lsb) >> 16);
}
__device__ __forceinline__ u32 bfpk(float a, float b) {
  return (u32)f2bf(a) | ((u32)f2bf(b) << 16);
}
__device__ __forceinline__ bf16x8 ldfrag(const unsigned short* p) {
  return __builtin_bit_cast(bf16x8, *reinterpret_cast<const uint4*>(p));
}
__device__ __forceinline__ u32 comb2(u32 ps, u32 pf, float a, float na) {
  float r0 = a * bf2f((unsigned short)(ps & 0xffffu)) + na * bf2f((unsigned short)(pf & 0xffffu));
  float r1 = a * bf2f((unsigned short)(ps >> 16)) + na * bf2f((unsigned short)(pf >> 16));
  return (u32)f2bf(r0) | ((u32)f2bf(r1) << 16);
}

// ---------------------------------------------------------------------------
// FUSED kernel (R18 = R17 with launch_bounds (256,3)): LDS ~53 KB allows
// 3 blocks/CU; second launch_bounds arg behaves as min-blocks/CU (R14
// evidence: (512,4) -> cap 64 = 512/(4blk*2w)); (256,3) -> cap ~170 >= 104
// natural, so no spill risk, and declares 3-block residency intent.
// ---------------------------------------------------------------------------
#define AP 136   // bf16 row pitch (272 B); 68 dwords

__launch_bounds__(256, 3)
__global__ void fused_kernel(const float* __restrict__ x,
                             const float* __restrict__ adj,
                             const float* __restrict__ w1,
                             const float* __restrict__ w2,
                             const float* __restrict__ alpha_p,
                             const float* __restrict__ bin_score,
                             const float* __restrict__ fc2w, const float* __restrict__ fc2b,
                             const float* __restrict__ fc3w, const float* __restrict__ fc3b,
                             const float* __restrict__ ln1g, const float* __restrict__ ln1b,
                             const float* __restrict__ ln2g, const float* __restrict__ ln2b,
                             unsigned short* __restrict__ lnadj,
                             unsigned short* __restrict__ lnfeats)
{
  __shared__ __align__(16) u32 Ksh[64 * 68];               // 17408 B: K0 -> P0 -> Pc
  __shared__ __align__(16) u32 vhs[2][64];
  __shared__ __align__(16) u32 uhs[2][32];
  __shared__ __align__(16) unsigned short adjb[64 * AP];   // 17408 B: actw / adj halves / xfT / ob1
  __shared__ __align__(16) unsigned short Z1T[64 * AP];    // 17408 B: K1 -> P1 -> Z1 -> ob2
  __shared__ float red[16];

  const int tid = threadIdx.x;
  const int wv = tid >> 6;
  const int lane = tid & 63;
  const int l15 = lane & 15, q = lane >> 4;
  const int b = blockIdx.x;
  u32* K1u = reinterpret_cast<u32*>(Z1T);

  // ======================= Phase A: scores -> K ==========================
  {
    const int sw = wv & 1;               // stream
    const int mtbase = (wv >> 1) * 4;    // slice half
    const float* wm = sw ? w2 : w1;
    const float* fw = sw ? fc3w : fc2w;
    const float* fb = sw ? fc3b : fc2b;
    unsigned short* Kshh = sw ? Z1T : reinterpret_cast<unsigned short*>(Ksh);
    unsigned short* actw = adjb + (size_t)wv * (16 * AP);  // per-wave scratch

    uint4 wA[4][4];
    #pragma unroll
    for (int at = 0; at < 4; ++at) {
      const float* wrow = wm + (size_t)(16 * at + l15) * 128;
      #pragma unroll
      for (int kt = 0; kt < 4; ++kt) {
        float4 va = *reinterpret_cast<const float4*>(wrow + 32 * kt + 8 * q);
        float4 vb = *reinterpret_cast<const float4*>(wrow + 32 * kt + 8 * q + 4);
        wA[at][kt] = make_uint4(bfpk(va.x, va.y), bfpk(va.z, va.w),
                                bfpk(vb.x, vb.y), bfpk(vb.z, vb.w));
      }
    }
    uint4 fcwB[8];
    #pragma unroll
    for (int nt = 0; nt < 8; ++nt) {
      const int ch = 16 * nt + l15;
      uint4 o = make_uint4(0u, 0u, 0u, 0u);
      if (sw) {
        if (q < 2) {
          const float* fr = fw + (size_t)ch * 16 + 8 * q;
          float4 va = *reinterpret_cast<const float4*>(fr);
          float4 vb = *reinterpret_cast<const float4*>(fr + 4);
          o = make_uint4(bfpk(va.x, va.y), bfpk(va.z, va.w),
                         bfpk(vb.x, vb.y), bfpk(vb.z, vb.w));
        }
      } else {
        if (q == 0) o.x = bfpk(fw[ch * 2], fw[ch * 2 + 1]);
      }
      fcwB[nt] = o;
    }
    float bb[8];
    #pragma unroll
    for (int nt = 0; nt < 8; ++nt) bb[nt] = fb[16 * nt + l15];

    uint4 xa[4];
    #pragma unroll
    for (int mi = 0; mi < 4; ++mi) {
      const int node = 16 * (mtbase + mi) + l15;
      const float* xp = x + ((size_t)b * NN + node) * IND + (sw ? 2 : 0);
      uint4 o = make_uint4(0u, 0u, 0u, 0u);
      if (sw) {
        if (q < 2) {
          float2 p0 = *reinterpret_cast<const float2*>(xp + 8 * q);
          float2 p1 = *reinterpret_cast<const float2*>(xp + 8 * q + 2);
          float2 p2 = *reinterpret_cast<const float2*>(xp + 8 * q + 4);
          float2 p3 = *reinterpret_cast<const float2*>(xp + 8 * q + 6);
          o = make_uint4(bfpk(p0.x, p0.y), bfpk(p1.x, p1.y),
                         bfpk(p2.x, p2.y), bfpk(p3.x, p3.y));
        }
      } else {
        if (q == 0) {
          float2 p0 = *reinterpret_cast<const float2*>(xp);
          o.x = bfpk(p0.x, p0.y);
        }
      }
      xa[mi] = o;
    }

    #pragma unroll
    for (int mi = 0; mi < 4; ++mi) {
      const int mt = mtbase + mi;
      f32x4 acc[8];
      #pragma unroll
      for (int nt = 0; nt < 8; ++nt)
        acc[nt] = __builtin_amdgcn_mfma_f32_16x16x32_bf16(
            __builtin_bit_cast(bf16x8, xa[mi]), __builtin_bit_cast(bf16x8, fcwB[nt]),
            f32x4{0.f, 0.f, 0.f, 0.f}, 0, 0, 0);
      #pragma unroll
      for (int nt = 0; nt < 8; ++nt) {
        #pragma unroll
        for (int r = 0; r < 4; ++r) {
          float v = fmaxf(acc[nt][r] + bb[nt], 0.0f);
          actw[(4 * q + r) * AP + 16 * nt + l15] = f2bf(v);
        }
      }
      uint4 sB[4];
      #pragma unroll
      for (int kt = 0; kt < 4; ++kt)
        sB[kt] = *reinterpret_cast<const uint4*>(&actw[l15 * AP + 32 * kt + 8 * q]);
      #pragma unroll
      for (int at = 0; at < 4; ++at) {
        f32x4 sa = f32x4{0.f, 0.f, 0.f, 0.f};
        #pragma unroll
        for (int kt = 0; kt < 4; ++kt)
          sa = __builtin_amdgcn_mfma_f32_16x16x32_bf16(
              __builtin_bit_cast(bf16x8, wA[at][kt]), __builtin_bit_cast(bf16x8, sB[kt]),
              sa, 0, 0, 0);
        #pragma unroll
        for (int r = 0; r < 4; ++r) {
          float kv = fminf(__expf(fmaxf(sa[r], 0.0f)), 60000.0f);
          Kshh[(16 * at + 4 * q + r) * AP + 16 * mt + l15] =
              __half_as_ushort(__float2half_rn(kv));
        }
      }
    }
  }
  __syncthreads();   // K0 (Ksh), K1 (Z1T) complete; actw (adjb) dead

  const float ebs = __expf(bin_score[0]);

  // ============== Phase B: Sinkhorn (waves 0-1) | adj h0 (waves 2-3) =====
  if (wv < 2) {
    const int l = lane;
    u32* Ks = (wv == 0) ? Ksh : K1u;
    u32 kr[64];
    #pragma unroll
    for (int t = 0; t < 16; ++t) {
      uint4 kv = *reinterpret_cast<const uint4*>(Ks + l * 68 + 4 * t);
      kr[4 * t + 0] = kv.x; kr[4 * t + 1] = kv.y;
      kr[4 * t + 2] = kv.z; kr[4 * t + 3] = kv.w;
    }
    u32 kta[32], ktb[32];
    #pragma unroll
    for (int j = 0; j < 32; ++j) {
      u32 d0 = Ks[(2 * j) * 68 + l];
      u32 d1 = Ks[(2 * j + 1) * 68 + l];
      kta[j] = (d0 & 0xffffu) | (d1 << 16);
      ktb[j] = (d0 >> 16) | (d1 & 0xffff0000u);
    }

    u32* vh = vhs[wv];
    u32* uh = uhs[wv];
    vh[l] = 0x3C003C00u;
    float v128 = 1.0f, sum_v = 129.0f;
    float u_old = 0.0f, vo0 = 1.0f, vo1 = 1.0f;
    float ur = 0.0f;
    const float TOL = 1.5e-3f;

    for (int it = 0; it < 100; ++it) {
      const float u64v = 128.0f * rcpf_(ebs * sum_v);
      float a0 = ebs * v128, a1 = 0.f, a2 = 0.f, a3 = 0.f;
      const uint4* vh4 = reinterpret_cast<const uint4*>(vh);
      #pragma unroll
      for (int t = 0; t < 16; ++t) {
        uint4 vvv = vh4[t];
        a0 = fdot2f(kr[4 * t + 0], vvv.x, a0);
        a1 = fdot2f(kr[4 * t + 1], vvv.y, a1);
        a2 = fdot2f(kr[4 * t + 2], vvv.z, a2);
        a3 = fdot2f(kr[4 * t + 3], vvv.w, a3);
      }
      float urn = rcpf_((a0 + a1) + (a2 + a3));
      float m1 = fabsf(urn - u_old) - TOL * urn;
      u_old = urn; ur = urn;
      float su = urn;
      su += __shfl_xor(su, 1);  su += __shfl_xor(su, 2);
      su += __shfl_xor(su, 4);  su += __shfl_xor(su, 8);
      su += __shfl_xor(su, 16); su += __shfl_xor(su, 32);
      const float sum_u = su + u64v;
      const float v128n = 64.0f * rcpf_(ebs * sum_u);
      float upr = __shfl_xor(urn, 1);
      if (!(l & 1)) uh[l >> 1] = pk2(urn, upr);
      float c0a = ebs * u64v, c0b = 0.f, c1a = ebs * u64v, c1b = 0.f;
      const uint4* uh4 = reinterpret_cast<const uint4*>(uh);
      #pragma unroll
      for (int t = 0; t < 8; ++t) {
        uint4 uu = uh4[t];
        c0a = fdot2f(kta[4 * t + 0], uu.x, c0a);
        c0b = fdot2f(kta[4 * t + 1], uu.y, c0b);
        c0a = fdot2f(kta[4 * t + 2], uu.z, c0a);
        c0b = fdot2f(kta[4 * t + 3], uu.w, c0b);
        c1a = fdot2f(ktb[4 * t + 0], uu.x, c1a);
        c1b = fdot2f(ktb[4 * t + 1], uu.y, c1b);
        c1a = fdot2f(ktb[4 * t + 2], uu.z, c1a);
        c1b = fdot2f(ktb[4 * t + 3], uu.w, c1b);
      }
      float v0n = rcpf_(c0a + c0b);
      float v1n = rcpf_(c1a + c1b);
      float m2 = fabsf(v0n - vo0) - TOL * v0n;
      float m3 = fabsf(v1n - vo1) - TOL * v1n;
      vo0 = v0n; vo1 = v1n;
      vh[l] = pk2(v0n, v1n);
      float sv = v0n + v1n;
      sv += __shfl_xor(sv, 1);  sv += __shfl_xor(sv, 2);
      sv += __shfl_xor(sv, 4);  sv += __shfl_xor(sv, 8);
      sv += __shfl_xor(sv, 16); sv += __shfl_xor(sv, 32);
      sum_v = sv + v128n;
      v128 = v128n;
      float mcond = fmaxf(m1, fmaxf(m2, m3));
      if (__all(mcond <= 0.0f)) break;
    }

    // P = K*u*v (bf16) IN PLACE over Ks
    {
      const uint4* vh4 = reinterpret_cast<const uint4*>(vh);
      #pragma unroll
      for (int t = 0; t < 16; ++t) {
        uint4 vvv = vh4[t];
        u32 o0 = bfpk(h_lo(kr[4 * t + 0]) * ur * h_lo(vvv.x),
                      h_hi(kr[4 * t + 0]) * ur * h_hi(vvv.x));
        u32 o1 = bfpk(h_lo(kr[4 * t + 1]) * ur * h_lo(vvv.y),
                      h_hi(kr[4 * t + 1]) * ur * h_hi(vvv.y));
        u32 o2 = bfpk(h_lo(kr[4 * t + 2]) * ur * h_lo(vvv.z),
                      h_hi(kr[4 * t + 2]) * ur * h_hi(vvv.z));
        u32 o3 = bfpk(h_lo(kr[4 * t + 3]) * ur * h_lo(vvv.w),
                      h_hi(kr[4 * t + 3]) * ur * h_hi(vvv.w));
        *reinterpret_cast<uint4*>(&Ks[l * 68 + 4 * t]) = make_uint4(o0, o1, o2, o3);
      }
    }
  } else {
    // stage adj rows 0..63 -> adjb (128 threads)
    const float4* src = reinterpret_cast<const float4*>(adj + (size_t)b * (NN * NN));
    for (int i = tid - 128; i < 64 * 32; i += 128) {
      int row = i >> 5, c4 = i & 31;
      float4 v = src[i];
      u32 w0 = (u32)f2bf(v.x) | ((u32)f2bf(v.y) << 16);
      u32 w1 = (u32)f2bf(v.z) | ((u32)f2bf(v.w) << 16);
      *reinterpret_cast<uint2*>(&adjb[row * AP + c4 * 4]) = make_uint2(w0, w1);
    }
  }
  __syncthreads();   // P0 (Ksh), P1 (Z1T); adjb h0 staged

  // ======================= Phase C: align ================================
  const float aa = 1.0f / (1.0f + __expf(-alpha_p[0]));
  const float na = 1.0f - aa;
  for (int i = tid; i < 4096; i += 256) {
    int row = i >> 6, cd = i & 63;
    Ksh[row * 68 + cd] = comb2(Ksh[row * 68 + cd], K1u[row * 68 + cd], aa, na);
  }
  __syncthreads();   // Pc ready; P1 (Z1T) dead
  const unsigned short* Pc = reinterpret_cast<const unsigned short*>(Ksh);

  // M1 half 0
  {
    f32x4 acch[4];
    #pragma unroll
    for (int j = 0; j < 4; ++j) acch[j] = f32x4{0.f, 0.f, 0.f, 0.f};
    #pragma unroll
    for (int kt = 0; kt < 4; ++kt) {
      const int d0 = 32 * kt + 8 * q;
      bf16x8 af = ldfrag(&adjb[(16 * wv + l15) * AP + d0]);
      #pragma unroll
      for (int j = 0; j < 4; ++j) {
        bf16x8 bf = ldfrag(&Pc[(16 * j + l15) * AP + d0]);
        acch[j] = __builtin_amdgcn_mfma_f32_16x16x32_bf16(af, bf, acch[j], 0, 0, 0);
      }
    }
    __syncthreads();   // all combine reads of Z1T done block-wide
    #pragma unroll
    for (int j = 0; j < 4; ++j) {
      const int k = 16 * j + l15;
      const int nbase = 16 * wv + 4 * q;
      u32 w0 = (u32)f2bf(acch[j][0]) | ((u32)f2bf(acch[j][1]) << 16);
      u32 w1 = (u32)f2bf(acch[j][2]) | ((u32)f2bf(acch[j][3]) << 16);
      *reinterpret_cast<uint2*>(&Z1T[k * AP + nbase]) = make_uint2(w0, w1);
    }
  }
  __syncthreads();   // adjb h0 reads done

  // stage adj rows 64..127
  {
    const float4* src = reinterpret_cast<const float4*>(
        adj + (size_t)b * (NN * NN) + (size_t)64 * NN);
    for (int i = tid; i < 64 * 32; i += 256) {
      int row = i >> 5, c4 = i & 31;
      float4 v = src[i];
      u32 w0 = (u32)f2bf(v.x) | ((u32)f2bf(v.y) << 16);
      u32 w1 = (u32)f2bf(v.z) | ((u32)f2bf(v.w) << 16);
      *reinterpret_cast<uint2*>(&adjb[row * AP + c4 * 4]) = make_uint2(w0, w1);
    }
  }
  __syncthreads();

  // M1 half 1
  {
    f32x4 acch[4];
    #pragma unroll
    for (int j = 0; j < 4; ++j) acch[j] = f32x4{0.f, 0.f, 0.f, 0.f};
    #pragma unroll
    for (int kt = 0; kt < 4; ++kt) {
      const int d0 = 32 * kt + 8 * q;
      bf16x8 af = ldfrag(&adjb[(16 * wv + l15) * AP + d0]);
      #pragma unroll
      for (int j = 0; j < 4; ++j) {
        bf16x8 bf = ldfrag(&Pc[(16 * j + l15) * AP + d0]);
        acch[j] = __builtin_amdgcn_mfma_f32_16x16x32_bf16(af, bf, acch[j], 0, 0, 0);
      }
    }
    #pragma unroll
    for (int j = 0; j < 4; ++j) {
      const int k = 16 * j + l15;
      const int nbase = 64 + 16 * wv + 4 * q;
      u32 w0 = (u32)f2bf(acch[j][0]) | ((u32)f2bf(acch[j][1]) << 16);
      u32 w1 = (u32)f2bf(acch[j][2]) | ((u32)f2bf(acch[j][3]) << 16);
      *reinterpret_cast<uint2*>(&Z1T[k * AP + nbase]) = make_uint2(w0, w1);
    }
  }
  __syncthreads();   // Z1T complete; adjb free

  // stage xfT into adjb tail
  unsigned short* xfT = adjb + 48 * AP;
  for (int i = tid; i < 2048; i += 256) {
    int n = i & 127, f = i >> 7;
    xfT[f * AP + n] = f2bf(x[((size_t)b * NN + n) * IND + 2 + f]);
  }
  __syncthreads();

  // M2: al2 = Pc @ Z1 ; M3: feats = Pc @ xf
  f32x4 acc2[4];
  f32x4 acc3 = f32x4{0.f, 0.f, 0.f, 0.f};
  #pragma unroll
  for (int j = 0; j < 4; ++j) acc2[j] = f32x4{0.f, 0.f, 0.f, 0.f};
  #pragma unroll
  for (int nt = 0; nt < 4; ++nt) {
    const int n0 = 32 * nt + 8 * q;
    bf16x8 af = ldfrag(&Pc[(16 * wv + l15) * AP + n0]);
    #pragma unroll
    for (int j = 0; j < 4; ++j) {
      bf16x8 bv = ldfrag(&Z1T[(16 * j + l15) * AP + n0]);
      acc2[j] = __builtin_amdgcn_mfma_f32_16x16x32_bf16(af, bv, acc2[j], 0, 0, 0);
    }
    bf16x8 bx = ldfrag(&xfT[l15 * AP + n0]);
    acc3 = __builtin_amdgcn_mfma_f32_16x16x32_bf16(af, bx, acc3, 0, 0, 0);
  }

  // LN reductions
  {
    float s1 = 0.f, q1 = 0.f, s2 = 0.f, q2 = 0.f;
    #pragma unroll
    for (int j = 0; j < 4; ++j)
      #pragma unroll
      for (int r = 0; r < 4; ++r) { float v = acc2[j][r]; s1 += v; q1 += v * v; }
    #pragma unroll
    for (int r = 0; r < 4; ++r) { float v = acc3[r]; s2 += v; q2 += v * v; }
    #pragma unroll
    for (int off = 1; off < 64; off <<= 1) {
      s1 += __shfl_xor(s1, off); q1 += __shfl_xor(q1, off);
      s2 += __shfl_xor(s2, off); q2 += __shfl_xor(q2, off);
    }
    if (lane == 0) { red[wv] = s1; red[4 + wv] = q1; red[8 + wv] = s2; red[12 + wv] = q2; }
  }
  __syncthreads();
  const float S1 = red[0] + red[1] + red[2] + red[3];
  const float Q1 = red[4] + red[5] + red[6] + red[7];
  const float S2 = red[8] + red[9] + red[10] + red[11];
  const float Q2 = red[12] + red[13] + red[14] + red[15];
  const float mean1 = S1 * (1.0f / 4096.0f);
  const float rstd1 = rsqrtf(Q1 * (1.0f / 4096.0f) - mean1 * mean1 + 1e-5f);
  const float mean2 = S2 * (1.0f / 1024.0f);
  const float rstd2 = rsqrtf(Q2 * (1.0f / 1024.0f) - mean2 * mean2 + 1e-5f);

  // normalize + bounce through freed LDS
  unsigned short* ob1 = adjb;
  unsigned short* ob2 = Z1T;
  #pragma unroll
  for (int j = 0; j < 4; ++j) {
    const int k = 16 * j + l15;
    #pragma unroll
    for (int r = 0; r < 4; ++r) {
      const int m = 16 * wv + 4 * q + r;
      const int pos = m * 64 + k;
      float vv2 = (acc2[j][r] - mean1) * rstd1 * ln1g[pos] + ln1b[pos];
      ob1[pos] = f2bf(vv2);
    }
  }
  {
    const int f = l15;
    #pragma unroll
    for (int r = 0; r < 4; ++r) {
      const int m = 16 * wv + 4 * q + r;
      const int pos = m * 16 + f;
      float vv2 = (acc3[r] - mean2) * rstd2 * ln2g[pos] + ln2b[pos];
      ob2[pos] = f2bf(vv2);
    }
  }
  __syncthreads();
  {
    const uint4* sp = reinterpret_cast<const uint4*>(ob1);
    uint4* dp = reinterpret_cast<uint4*>(lnadj + (size_t)b * 4096);
    for (int i = tid; i < 512; i += 256) dp[i] = sp[i];
    if (tid < 128)
      reinterpret_cast<uint4*>(lnfeats + (size_t)b * 1024)[tid] =
          reinterpret_cast<const uint4*>(ob2)[tid];
  }
}

// ---------------------------------------------------------------------------
// TAIL kernel (R16, unchanged): fc4 + fc5 + fc6^T transpose in ONE dispatch.
// ---------------------------------------------------------------------------
#define GP 72
__launch_bounds__(256, 2)
__global__ void tail_kernel(const unsigned short* __restrict__ lnadj,
                            const float* __restrict__ fc4w, const float* __restrict__ fc4b,
                            const unsigned short* __restrict__ lnfeats,
                            const float* __restrict__ fc5w, const float* __restrict__ fc5b,
                            const float* __restrict__ fc6w,
                            float* __restrict__ h45,
                            float* __restrict__ wT6)
{
  const int tid = threadIdx.x;
  const int by = blockIdx.y;

  if (by == 8) {
    int idx = blockIdx.x * 256 + tid;
    for (; idx < 64 * 512; idx += 32 * 256) {
      int rr = idx >> 9, cc = idx & 511;
      wT6[cc * 64 + rr] = fc6w[idx];
    }
    return;
  }

  __shared__ __align__(16) unsigned short At[64 * GP];
  __shared__ __align__(16) unsigned short Wt[64 * GP];
  const bool is4 = (by < 4);
  const unsigned short* A = is4 ? lnadj : lnfeats;
  const float* W = is4 ? fc4w : fc5w;
  const float* bias = is4 ? fc4b : fc5b;
  const int K = is4 ? 4096 : 1024;
  const int coff = is4 ? 0 : 256;
  const int m0 = blockIdx.x * 64;
  const int n0 = (is4 ? by : (by - 4)) * 64;
  const int w = tid >> 6, lane = tid & 63;
  const int l15 = lane & 15, q = lane >> 4;
  const int srow = tid >> 2, sko = (tid & 3) * 16;

  f32x4 acc[4];
  #pragma unroll
  for (int j = 0; j < 4; ++j) acc[j] = f32x4{0.f, 0.f, 0.f, 0.f};

  for (int kc = 0; kc < K; kc += 64) {
    __syncthreads();
    {
      const unsigned short* ap = &A[(size_t)(m0 + srow) * K + kc + sko];
      *reinterpret_cast<uint4*>(&At[srow * GP + sko]) =
          *reinterpret_cast<const uint4*>(ap);
      *reinterpret_cast<uint4*>(&At[srow * GP + sko + 8]) =
          *reinterpret_cast<const uint4*>(ap + 8);
      const float* wp = &W[(size_t)(n0 + srow) * K + kc + sko];
      const float4 v0 = reinterpret_cast<const float4*>(wp)[0];
      const float4 v1 = reinterpret_cast<const float4*>(wp)[1];
      const float4 v2 = reinterpret_cast<const float4*>(wp)[2];
      const float4 v3 = reinterpret_cast<const float4*>(wp)[3];
      uint4 o0, o1;
      o0.x = (u32)f2bf(v0.x) | ((u32)f2bf(v0.y) << 16);
      o0.y = (u32)f2bf(v0.z) | ((u32)f2bf(v0.w) << 16);
      o0.z = (u32)f2bf(v1.x) | ((u32)f2bf(v1.y) << 16);
      o0.w = (u32)f2bf(v1.z) | ((u32)f2bf(v1.w) << 16);
      o1.x = (u32)f2bf(v2.x) | ((u32)f2bf(v2.y) << 16);
      o1.y = (u32)f2bf(v2.z) | ((u32)f2bf(v2.w) << 16);
      o1.z = (u32)f2bf(v3.x) | ((u32)f2bf(v3.y) << 16);
      o1.w = (u32)f2bf(v3.z) | ((u32)f2bf(v3.w) << 16);
      *reinterpret_cast<uint4*>(&Wt[srow * GP + sko]) = o0;
      *reinterpret_cast<uint4*>(&Wt[srow * GP + sko + 8]) = o1;
    }
    __syncthreads();
    #pragma unroll
    for (int s = 0; s < 2; ++s) {
      bf16x8 af = ldfrag(&At[(16 * w + l15) * GP + 32 * s + 8 * q]);
      #pragma unroll
      for (int j = 0; j < 4; ++j) {
        bf16x8 bf = ldfrag(&Wt[(16 * j + l15) * GP + 32 * s + 8 * q]);
        acc[j] = __builtin_amdgcn_mfma_f32_16x16x32_bf16(af, bf, acc[j], 0, 0, 0);
      }
    }
  }
  #pragma unroll
  for (int j = 0; j < 4; ++j) {
    const int col = n0 + 16 * j + l15;
    const float bb = bias[col];
    #pragma unroll
    for (int r = 0; r < 4; ++r) {
      const int m = m0 + 16 * w + 4 * q + r;
      h45[(size_t)m * 512 + coff + col] = fmaxf(acc[j][r] + bb, 0.0f);
    }
  }
}

// ---------------------------------------------------------------------------
// Kernel D: unchanged (8 rows/block).
// ---------------------------------------------------------------------------
__launch_bounds__(256)
__global__ void head_kernel(const float* __restrict__ h45,
                            const float* __restrict__ wT6,   // [512][64]
                            const float* __restrict__ b6,
                            const float* __restrict__ w7,    // [10][64]
                            const float* __restrict__ b7,
                            float* __restrict__ out)
{
  __shared__ float row[8][512];
  __shared__ float h6[8][64];
  __shared__ float zb[8][12];
  const int tid = threadIdx.x;
  const int r0 = blockIdx.x * 8;
  for (int i = tid; i < 8 * 128; i += 256) {
    int r = i >> 7, c4 = i & 127;
    *reinterpret_cast<float4*>(&row[r][c4 * 4]) =
        reinterpret_cast<const float4*>(h45 + (size_t)(r0 + r) * 512)[c4];
  }
  __syncthreads();
  const int o = tid & 63, rg = tid >> 6;
  float a0 = b6[o], a1 = a0;
  #pragma unroll 8
  for (int k = 0; k < 512; ++k) {
    float wv = wT6[k * 64 + o];
    a0 += row[rg][k] * wv;
    a1 += row[rg + 4][k] * wv;
  }
  h6[rg][o] = fmaxf(a0, 0.0f);
  h6[rg + 4][o] = fmaxf(a1, 0.0f);
  __syncthreads();
  if (tid < 80) {
    int r = tid / 10, c = tid - r * 10;
    float z = b7[c];
    #pragma unroll
    for (int k = 0; k < 64; ++k) z += h6[r][k] * w7[c * 64 + k];
    zb[r][c] = z;
  }
  __syncthreads();
  if (tid < 80) {
    int r = tid / 10, c = tid - r * 10;
    float mx = zb[r][0];
    #pragma unroll
    for (int j = 1; j < 10; ++j) mx = fmaxf(mx, zb[r][j]);
    float se = 0.f;
    #pragma unroll
    for (int j = 0; j < 10; ++j) se += __expf(zb[r][j] - mx);
    out[(size_t)(r0 + r) * 10 + c] = zb[r][c] - mx - __logf(se);
  }
}

// ---------------------------------------------------------------------------
extern "C" void kernel_launch(void* const* d_in, const int* in_sizes, int n_in,
                              void* d_out, int out_size, void* d_ws, size_t ws_size,
                              hipStream_t stream)
{
  (void)in_sizes; (void)n_in; (void)out_size; (void)ws_size;
  const float* x    = (const float*)d_in[0];
  const float* adj  = (const float*)d_in[1];
  const float* w1   = (const float*)d_in[2];
  const float* w2   = (const float*)d_in[3];
  const float* alpha = (const float*)d_in[4];
  const float* bin_score = (const float*)d_in[5];
  const float* fc2w = (const float*)d_in[6];
  const float* fc2b = (const float*)d_in[7];
  const float* fc3w = (const float*)d_in[8];
  const float* fc3b = (const float*)d_in[9];
  const float* ln1g = (const float*)d_in[10];
  const float* ln1b = (const float*)d_in[11];
  const float* fc4w = (const float*)d_in[12];
  const float* fc4b = (const float*)d_in[13];
  const float* ln2g = (const float*)d_in[14];
  const float* ln2b = (const float*)d_in[15];
  const float* fc5w = (const float*)d_in[16];
  const float* fc5b = (const float*)d_in[17];
  const float* fc6w = (const float*)d_in[18];
  const float* fc6b = (const float*)d_in[19];
  const float* fc7w = (const float*)d_in[20];
  const float* fc7b = (const float*)d_in[21];
  float* out = (float*)d_out;

  char* ws = (char*)d_ws;
  size_t off = 0;
  unsigned short* lnadj = (unsigned short*)(ws + off);  off += (size_t)2048 * 4096 * 2;
  unsigned short* lnfeats = (unsigned short*)(ws + off); off += (size_t)2048 * 1024 * 2;
  float* h45 = (float*)(ws + off);                      off += (size_t)2048 * 512 * 4;
  float* wT6 = (float*)(ws + off);                      off += (size_t)512 * 64 * 4;

  hipLaunchKernelGGL(fused_kernel, dim3(2048), dim3(256), 0, stream,
                     x, adj, w1, w2, alpha, bin_score,
                     fc2w, fc2b, fc3w, fc3b,
                     ln1g, ln1b, ln2g, ln2b, lnadj, lnfeats);
  hipLaunchKernelGGL(tail_kernel, dim3(32, 9), dim3(256), 0, stream,
                     lnadj, fc4w, fc4b, lnfeats, fc5w, fc5b, fc6w, h45, wT6);
  hipLaunchKernelGGL(head_kernel, dim3(256), dim3(256), 0, stream,
                     h45, wT6, fc6b, fc7w, fc7b, out);
}

// Round 19
// 208.647 us; speedup vs baseline: 1.0955x; 1.0955x over previous
//
#include <hip/hip_runtime.h>
#include <hip/hip_bf16.h>
#include <hip/hip_fp16.h>

// Problem constants
#define B_   2048
#define NN   128    // NMAX
#define MM   64     // HN
#define HD_  128
#define IND  18
#define FD_  16

typedef unsigned int u32;
typedef _Float16 h2_t __attribute__((ext_vector_type(2)));
typedef __attribute__((ext_vector_type(8))) short bf16x8;
typedef __attribute__((ext_vector_type(4))) float f32x4;

__device__ __forceinline__ float fdot2f(u32 a, u32 b, float c) {
#if defined(__has_builtin)
#if __has_builtin(__builtin_amdgcn_fdot2)
  return __builtin_amdgcn_fdot2(__builtin_bit_cast(h2_t, a),
                                __builtin_bit_cast(h2_t, b), c, false);
#else
  h2_t x = __builtin_bit_cast(h2_t, a), y = __builtin_bit_cast(h2_t, b);
  return c + (float)x[0] * (float)y[0] + (float)x[1] * (float)y[1];
#endif
#else
  h2_t x = __builtin_bit_cast(h2_t, a), y = __builtin_bit_cast(h2_t, b);
  return c + (float)x[0] * (float)y[0] + (float)x[1] * (float)y[1];
#endif
}

__device__ __forceinline__ u32 pk2(float a, float b) {
#if defined(__has_builtin)
#if __has_builtin(__builtin_amdgcn_cvt_pkrtz)
  return __builtin_bit_cast(u32, __builtin_amdgcn_cvt_pkrtz(a, b));
#else
  __half ha = __float2half_rn(a), hb = __float2half_rn(b);
  return (u32)__half_as_ushort(ha) | ((u32)__half_as_ushort(hb) << 16);
#endif
#else
  __half ha = __float2half_rn(a), hb = __float2half_rn(b);
  return (u32)__half_as_ushort(ha) | ((u32)__half_as_ushort(hb) << 16);
#endif
}

__device__ __forceinline__ float rcpf_(float x) {
#if defined(__has_builtin)
#if __has_builtin(__builtin_amdgcn_rcpf)
  return __builtin_amdgcn_rcpf(x);
#else
  return 1.0f / x;
#endif
#else
  return 1.0f / x;
#endif
}

__device__ __forceinline__ float h_lo(u32 d) {
  return __half2float(__ushort_as_half((unsigned short)(d & 0xffffu)));
}
__device__ __forceinline__ float h_hi(u32 d) {
  return __half2float(__ushort_as_half((unsigned short)(d >> 16)));
}

__device__ __forceinline__ float bf2f(unsigned short u) {
  union { float f; u32 i; } z; z.i = ((u32)u) << 16; return z.f;
}
__device__ __forceinline__ unsigned short f2bf(float f) {
  union { float fv; u32 u; } z; z.fv = f;
  u32 lsb = (z.u >> 16) & 1u;
  return (unsigned short)((z.u + 0x7fffu + lsb) >> 16);
}
__device__ __forceinline__ u32 bfpk(float a, float b) {
  return (u32)f2bf(a) | ((u32)f2bf(b) << 16);
}
__device__ __forceinline__ bf16x8 ldfrag(const unsigned short* p) {
  return __builtin_bit_cast(bf16x8, *reinterpret_cast<const uint4*>(p));
}
__device__ __forceinline__ u32 comb2(u32 ps, u32 pf, float a, float na) {
  float r0 = a * bf2f((unsigned short)(ps & 0xffffu)) + na * bf2f((unsigned short)(pf & 0xffffu));
  float r1 = a * bf2f((unsigned short)(ps >> 16)) + na * bf2f((unsigned short)(pf >> 16));
  return (u32)f2bf(r0) | ((u32)f2bf(r1) << 16);
}

// ---------------------------------------------------------------------------
// FUSED kernel (R19 = R17 with launch_bounds(256) — no min-waves arg).
// LDS ~53 KB => 3 blocks/CU fit by LDS; natural VGPR ~104 => 4 waves/SIMD
// allowed. R18 proved 3 blocks DO schedule at this LDS ((256,3) -> Occ 31%)
// but its VGPR cap 84 spilled (FETCH 150MB). No-arg should keep VGPR=104
// (R13/R16/R17 bodies identical) AND let the scheduler fit 3 blocks.
// ---------------------------------------------------------------------------
#define AP 136   // bf16 row pitch (272 B); 68 dwords

__launch_bounds__(256)
__global__ void fused_kernel(const float* __restrict__ x,
                             const float* __restrict__ adj,
                             const float* __restrict__ w1,
                             const float* __restrict__ w2,
                             const float* __restrict__ alpha_p,
                             const float* __restrict__ bin_score,
                             const float* __restrict__ fc2w, const float* __restrict__ fc2b,
                             const float* __restrict__ fc3w, const float* __restrict__ fc3b,
                             const float* __restrict__ ln1g, const float* __restrict__ ln1b,
                             const float* __restrict__ ln2g, const float* __restrict__ ln2b,
                             unsigned short* __restrict__ lnadj,
                             unsigned short* __restrict__ lnfeats)
{
  __shared__ __align__(16) u32 Ksh[64 * 68];               // 17408 B: K0 -> P0 -> Pc
  __shared__ __align__(16) u32 vhs[2][64];
  __shared__ __align__(16) u32 uhs[2][32];
  __shared__ __align__(16) unsigned short adjb[64 * AP];   // 17408 B: actw / adj halves / xfT / ob1
  __shared__ __align__(16) unsigned short Z1T[64 * AP];    // 17408 B: K1 -> P1 -> Z1 -> ob2
  __shared__ float red[16];

  const int tid = threadIdx.x;
  const int wv = tid >> 6;
  const int lane = tid & 63;
  const int l15 = lane & 15, q = lane >> 4;
  const int b = blockIdx.x;
  u32* K1u = reinterpret_cast<u32*>(Z1T);

  // ======================= Phase A: scores -> K ==========================
  {
    const int sw = wv & 1;               // stream
    const int mtbase = (wv >> 1) * 4;    // slice half
    const float* wm = sw ? w2 : w1;
    const float* fw = sw ? fc3w : fc2w;
    const float* fb = sw ? fc3b : fc2b;
    unsigned short* Kshh = sw ? Z1T : reinterpret_cast<unsigned short*>(Ksh);
    unsigned short* actw = adjb + (size_t)wv * (16 * AP);  // per-wave scratch

    uint4 wA[4][4];
    #pragma unroll
    for (int at = 0; at < 4; ++at) {
      const float* wrow = wm + (size_t)(16 * at + l15) * 128;
      #pragma unroll
      for (int kt = 0; kt < 4; ++kt) {
        float4 va = *reinterpret_cast<const float4*>(wrow + 32 * kt + 8 * q);
        float4 vb = *reinterpret_cast<const float4*>(wrow + 32 * kt + 8 * q + 4);
        wA[at][kt] = make_uint4(bfpk(va.x, va.y), bfpk(va.z, va.w),
                                bfpk(vb.x, vb.y), bfpk(vb.z, vb.w));
      }
    }
    uint4 fcwB[8];
    #pragma unroll
    for (int nt = 0; nt < 8; ++nt) {
      const int ch = 16 * nt + l15;
      uint4 o = make_uint4(0u, 0u, 0u, 0u);
      if (sw) {
        if (q < 2) {
          const float* fr = fw + (size_t)ch * 16 + 8 * q;
          float4 va = *reinterpret_cast<const float4*>(fr);
          float4 vb = *reinterpret_cast<const float4*>(fr + 4);
          o = make_uint4(bfpk(va.x, va.y), bfpk(va.z, va.w),
                         bfpk(vb.x, vb.y), bfpk(vb.z, vb.w));
        }
      } else {
        if (q == 0) o.x = bfpk(fw[ch * 2], fw[ch * 2 + 1]);
      }
      fcwB[nt] = o;
    }
    float bb[8];
    #pragma unroll
    for (int nt = 0; nt < 8; ++nt) bb[nt] = fb[16 * nt + l15];

    uint4 xa[4];
    #pragma unroll
    for (int mi = 0; mi < 4; ++mi) {
      const int node = 16 * (mtbase + mi) + l15;
      const float* xp = x + ((size_t)b * NN + node) * IND + (sw ? 2 : 0);
      uint4 o = make_uint4(0u, 0u, 0u, 0u);
      if (sw) {
        if (q < 2) {
          float2 p0 = *reinterpret_cast<const float2*>(xp + 8 * q);
          float2 p1 = *reinterpret_cast<const float2*>(xp + 8 * q + 2);
          float2 p2 = *reinterpret_cast<const float2*>(xp + 8 * q + 4);
          float2 p3 = *reinterpret_cast<const float2*>(xp + 8 * q + 6);
          o = make_uint4(bfpk(p0.x, p0.y), bfpk(p1.x, p1.y),
                         bfpk(p2.x, p2.y), bfpk(p3.x, p3.y));
        }
      } else {
        if (q == 0) {
          float2 p0 = *reinterpret_cast<const float2*>(xp);
          o.x = bfpk(p0.x, p0.y);
        }
      }
      xa[mi] = o;
    }

    #pragma unroll
    for (int mi = 0; mi < 4; ++mi) {
      const int mt = mtbase + mi;
      f32x4 acc[8];
      #pragma unroll
      for (int nt = 0; nt < 8; ++nt)
        acc[nt] = __builtin_amdgcn_mfma_f32_16x16x32_bf16(
            __builtin_bit_cast(bf16x8, xa[mi]), __builtin_bit_cast(bf16x8, fcwB[nt]),
            f32x4{0.f, 0.f, 0.f, 0.f}, 0, 0, 0);
      #pragma unroll
      for (int nt = 0; nt < 8; ++nt) {
        #pragma unroll
        for (int r = 0; r < 4; ++r) {
          float v = fmaxf(acc[nt][r] + bb[nt], 0.0f);
          actw[(4 * q + r) * AP + 16 * nt + l15] = f2bf(v);
        }
      }
      uint4 sB[4];
      #pragma unroll
      for (int kt = 0; kt < 4; ++kt)
        sB[kt] = *reinterpret_cast<const uint4*>(&actw[l15 * AP + 32 * kt + 8 * q]);
      #pragma unroll
      for (int at = 0; at < 4; ++at) {
        f32x4 sa = f32x4{0.f, 0.f, 0.f, 0.f};
        #pragma unroll
        for (int kt = 0; kt < 4; ++kt)
          sa = __builtin_amdgcn_mfma_f32_16x16x32_bf16(
              __builtin_bit_cast(bf16x8, wA[at][kt]), __builtin_bit_cast(bf16x8, sB[kt]),
              sa, 0, 0, 0);
        #pragma unroll
        for (int r = 0; r < 4; ++r) {
          float kv = fminf(__expf(fmaxf(sa[r], 0.0f)), 60000.0f);
          Kshh[(16 * at + 4 * q + r) * AP + 16 * mt + l15] =
              __half_as_ushort(__float2half_rn(kv));
        }
      }
    }
  }
  __syncthreads();   // K0 (Ksh), K1 (Z1T) complete; actw (adjb) dead

  const float ebs = __expf(bin_score[0]);

  // ============== Phase B: Sinkhorn (waves 0-1) | adj h0 (waves 2-3) =====
  if (wv < 2) {
    const int l = lane;
    u32* Ks = (wv == 0) ? Ksh : K1u;
    u32 kr[64];
    #pragma unroll
    for (int t = 0; t < 16; ++t) {
      uint4 kv = *reinterpret_cast<const uint4*>(Ks + l * 68 + 4 * t);
      kr[4 * t + 0] = kv.x; kr[4 * t + 1] = kv.y;
      kr[4 * t + 2] = kv.z; kr[4 * t + 3] = kv.w;
    }
    u32 kta[32], ktb[32];
    #pragma unroll
    for (int j = 0; j < 32; ++j) {
      u32 d0 = Ks[(2 * j) * 68 + l];
      u32 d1 = Ks[(2 * j + 1) * 68 + l];
      kta[j] = (d0 & 0xffffu) | (d1 << 16);
      ktb[j] = (d0 >> 16) | (d1 & 0xffff0000u);
    }

    u32* vh = vhs[wv];
    u32* uh = uhs[wv];
    vh[l] = 0x3C003C00u;
    float v128 = 1.0f, sum_v = 129.0f;
    float u_old = 0.0f, vo0 = 1.0f, vo1 = 1.0f;
    float ur = 0.0f;
    const float TOL = 1.5e-3f;

    for (int it = 0; it < 100; ++it) {
      const float u64v = 128.0f * rcpf_(ebs * sum_v);
      float a0 = ebs * v128, a1 = 0.f, a2 = 0.f, a3 = 0.f;
      const uint4* vh4 = reinterpret_cast<const uint4*>(vh);
      #pragma unroll
      for (int t = 0; t < 16; ++t) {
        uint4 vvv = vh4[t];
        a0 = fdot2f(kr[4 * t + 0], vvv.x, a0);
        a1 = fdot2f(kr[4 * t + 1], vvv.y, a1);
        a2 = fdot2f(kr[4 * t + 2], vvv.z, a2);
        a3 = fdot2f(kr[4 * t + 3], vvv.w, a3);
      }
      float urn = rcpf_((a0 + a1) + (a2 + a3));
      float m1 = fabsf(urn - u_old) - TOL * urn;
      u_old = urn; ur = urn;
      float su = urn;
      su += __shfl_xor(su, 1);  su += __shfl_xor(su, 2);
      su += __shfl_xor(su, 4);  su += __shfl_xor(su, 8);
      su += __shfl_xor(su, 16); su += __shfl_xor(su, 32);
      const float sum_u = su + u64v;
      const float v128n = 64.0f * rcpf_(ebs * sum_u);
      float upr = __shfl_xor(urn, 1);
      if (!(l & 1)) uh[l >> 1] = pk2(urn, upr);
      float c0a = ebs * u64v, c0b = 0.f, c1a = ebs * u64v, c1b = 0.f;
      const uint4* uh4 = reinterpret_cast<const uint4*>(uh);
      #pragma unroll
      for (int t = 0; t < 8; ++t) {
        uint4 uu = uh4[t];
        c0a = fdot2f(kta[4 * t + 0], uu.x, c0a);
        c0b = fdot2f(kta[4 * t + 1], uu.y, c0b);
        c0a = fdot2f(kta[4 * t + 2], uu.z, c0a);
        c0b = fdot2f(kta[4 * t + 3], uu.w, c0b);
        c1a = fdot2f(ktb[4 * t + 0], uu.x, c1a);
        c1b = fdot2f(ktb[4 * t + 1], uu.y, c1b);
        c1a = fdot2f(ktb[4 * t + 2], uu.z, c1a);
        c1b = fdot2f(ktb[4 * t + 3], uu.w, c1b);
      }
      float v0n = rcpf_(c0a + c0b);
      float v1n = rcpf_(c1a + c1b);
      float m2 = fabsf(v0n - vo0) - TOL * v0n;
      float m3 = fabsf(v1n - vo1) - TOL * v1n;
      vo0 = v0n; vo1 = v1n;
      vh[l] = pk2(v0n, v1n);
      float sv = v0n + v1n;
      sv += __shfl_xor(sv, 1);  sv += __shfl_xor(sv, 2);
      sv += __shfl_xor(sv, 4);  sv += __shfl_xor(sv, 8);
      sv += __shfl_xor(sv, 16); sv += __shfl_xor(sv, 32);
      sum_v = sv + v128n;
      v128 = v128n;
      float mcond = fmaxf(m1, fmaxf(m2, m3));
      if (__all(mcond <= 0.0f)) break;
    }

    // P = K*u*v (bf16) IN PLACE over Ks
    {
      const uint4* vh4 = reinterpret_cast<const uint4*>(vh);
      #pragma unroll
      for (int t = 0; t < 16; ++t) {
        uint4 vvv = vh4[t];
        u32 o0 = bfpk(h_lo(kr[4 * t + 0]) * ur * h_lo(vvv.x),
                      h_hi(kr[4 * t + 0]) * ur * h_hi(vvv.x));
        u32 o1 = bfpk(h_lo(kr[4 * t + 1]) * ur * h_lo(vvv.y),
                      h_hi(kr[4 * t + 1]) * ur * h_hi(vvv.y));
        u32 o2 = bfpk(h_lo(kr[4 * t + 2]) * ur * h_lo(vvv.z),
                      h_hi(kr[4 * t + 2]) * ur * h_hi(vvv.z));
        u32 o3 = bfpk(h_lo(kr[4 * t + 3]) * ur * h_lo(vvv.w),
                      h_hi(kr[4 * t + 3]) * ur * h_hi(vvv.w));
        *reinterpret_cast<uint4*>(&Ks[l * 68 + 4 * t]) = make_uint4(o0, o1, o2, o3);
      }
    }
  } else {
    // stage adj rows 0..63 -> adjb (128 threads)
    const float4* src = reinterpret_cast<const float4*>(adj + (size_t)b * (NN * NN));
    for (int i = tid - 128; i < 64 * 32; i += 128) {
      int row = i >> 5, c4 = i & 31;
      float4 v = src[i];
      u32 w0 = (u32)f2bf(v.x) | ((u32)f2bf(v.y) << 16);
      u32 w1 = (u32)f2bf(v.z) | ((u32)f2bf(v.w) << 16);
      *reinterpret_cast<uint2*>(&adjb[row * AP + c4 * 4]) = make_uint2(w0, w1);
    }
  }
  __syncthreads();   // P0 (Ksh), P1 (Z1T); adjb h0 staged

  // ======================= Phase C: align ================================
  const float aa = 1.0f / (1.0f + __expf(-alpha_p[0]));
  const float na = 1.0f - aa;
  for (int i = tid; i < 4096; i += 256) {
    int row = i >> 6, cd = i & 63;
    Ksh[row * 68 + cd] = comb2(Ksh[row * 68 + cd], K1u[row * 68 + cd], aa, na);
  }
  __syncthreads();   // Pc ready; P1 (Z1T) dead
  const unsigned short* Pc = reinterpret_cast<const unsigned short*>(Ksh);

  // M1 half 0
  {
    f32x4 acch[4];
    #pragma unroll
    for (int j = 0; j < 4; ++j) acch[j] = f32x4{0.f, 0.f, 0.f, 0.f};
    #pragma unroll
    for (int kt = 0; kt < 4; ++kt) {
      const int d0 = 32 * kt + 8 * q;
      bf16x8 af = ldfrag(&adjb[(16 * wv + l15) * AP + d0]);
      #pragma unroll
      for (int j = 0; j < 4; ++j) {
        bf16x8 bf = ldfrag(&Pc[(16 * j + l15) * AP + d0]);
        acch[j] = __builtin_amdgcn_mfma_f32_16x16x32_bf16(af, bf, acch[j], 0, 0, 0);
      }
    }
    __syncthreads();   // all combine reads of Z1T done block-wide
    #pragma unroll
    for (int j = 0; j < 4; ++j) {
      const int k = 16 * j + l15;
      const int nbase = 16 * wv + 4 * q;
      u32 w0 = (u32)f2bf(acch[j][0]) | ((u32)f2bf(acch[j][1]) << 16);
      u32 w1 = (u32)f2bf(acch[j][2]) | ((u32)f2bf(acch[j][3]) << 16);
      *reinterpret_cast<uint2*>(&Z1T[k * AP + nbase]) = make_uint2(w0, w1);
    }
  }
  __syncthreads();   // adjb h0 reads done

  // stage adj rows 64..127
  {
    const float4* src = reinterpret_cast<const float4*>(
        adj + (size_t)b * (NN * NN) + (size_t)64 * NN);
    for (int i = tid; i < 64 * 32; i += 256) {
      int row = i >> 5, c4 = i & 31;
      float4 v = src[i];
      u32 w0 = (u32)f2bf(v.x) | ((u32)f2bf(v.y) << 16);
      u32 w1 = (u32)f2bf(v.z) | ((u32)f2bf(v.w) << 16);
      *reinterpret_cast<uint2*>(&adjb[row * AP + c4 * 4]) = make_uint2(w0, w1);
    }
  }
  __syncthreads();

  // M1 half 1
  {
    f32x4 acch[4];
    #pragma unroll
    for (int j = 0; j < 4; ++j) acch[j] = f32x4{0.f, 0.f, 0.f, 0.f};
    #pragma unroll
    for (int kt = 0; kt < 4; ++kt) {
      const int d0 = 32 * kt + 8 * q;
      bf16x8 af = ldfrag(&adjb[(16 * wv + l15) * AP + d0]);
      #pragma unroll
      for (int j = 0; j < 4; ++j) {
        bf16x8 bf = ldfrag(&Pc[(16 * j + l15) * AP + d0]);
        acch[j] = __builtin_amdgcn_mfma_f32_16x16x32_bf16(af, bf, acch[j], 0, 0, 0);
      }
    }
    #pragma unroll
    for (int j = 0; j < 4; ++j) {
      const int k = 16 * j + l15;
      const int nbase = 64 + 16 * wv + 4 * q;
      u32 w0 = (u32)f2bf(acch[j][0]) | ((u32)f2bf(acch[j][1]) << 16);
      u32 w1 = (u32)f2bf(acch[j][2]) | ((u32)f2bf(acch[j][3]) << 16);
      *reinterpret_cast<uint2*>(&Z1T[k * AP + nbase]) = make_uint2(w0, w1);
    }
  }
  __syncthreads();   // Z1T complete; adjb free

  // stage xfT into adjb tail
  unsigned short* xfT = adjb + 48 * AP;
  for (int i = tid; i < 2048; i += 256) {
    int n = i & 127, f = i >> 7;
    xfT[f * AP + n] = f2bf(x[((size_t)b * NN + n) * IND + 2 + f]);
  }
  __syncthreads();

  // M2: al2 = Pc @ Z1 ; M3: feats = Pc @ xf
  f32x4 acc2[4];
  f32x4 acc3 = f32x4{0.f, 0.f, 0.f, 0.f};
  #pragma unroll
  for (int j = 0; j < 4; ++j) acc2[j] = f32x4{0.f, 0.f, 0.f, 0.f};
  #pragma unroll
  for (int nt = 0; nt < 4; ++nt) {
    const int n0 = 32 * nt + 8 * q;
    bf16x8 af = ldfrag(&Pc[(16 * wv + l15) * AP + n0]);
    #pragma unroll
    for (int j = 0; j < 4; ++j) {
      bf16x8 bv = ldfrag(&Z1T[(16 * j + l15) * AP + n0]);
      acc2[j] = __builtin_amdgcn_mfma_f32_16x16x32_bf16(af, bv, acc2[j], 0, 0, 0);
    }
    bf16x8 bx = ldfrag(&xfT[l15 * AP + n0]);
    acc3 = __builtin_amdgcn_mfma_f32_16x16x32_bf16(af, bx, acc3, 0, 0, 0);
  }

  // LN reductions
  {
    float s1 = 0.f, q1 = 0.f, s2 = 0.f, q2 = 0.f;
    #pragma unroll
    for (int j = 0; j < 4; ++j)
      #pragma unroll
      for (int r = 0; r < 4; ++r) { float v = acc2[j][r]; s1 += v; q1 += v * v; }
    #pragma unroll
    for (int r = 0; r < 4; ++r) { float v = acc3[r]; s2 += v; q2 += v * v; }
    #pragma unroll
    for (int off = 1; off < 64; off <<= 1) {
      s1 += __shfl_xor(s1, off); q1 += __shfl_xor(q1, off);
      s2 += __shfl_xor(s2, off); q2 += __shfl_xor(q2, off);
    }
    if (lane == 0) { red[wv] = s1; red[4 + wv] = q1; red[8 + wv] = s2; red[12 + wv] = q2; }
  }
  __syncthreads();
  const float S1 = red[0] + red[1] + red[2] + red[3];
  const float Q1 = red[4] + red[5] + red[6] + red[7];
  const float S2 = red[8] + red[9] + red[10] + red[11];
  const float Q2 = red[12] + red[13] + red[14] + red[15];
  const float mean1 = S1 * (1.0f / 4096.0f);
  const float rstd1 = rsqrtf(Q1 * (1.0f / 4096.0f) - mean1 * mean1 + 1e-5f);
  const float mean2 = S2 * (1.0f / 1024.0f);
  const float rstd2 = rsqrtf(Q2 * (1.0f / 1024.0f) - mean2 * mean2 + 1e-5f);

  // normalize + bounce through freed LDS
  unsigned short* ob1 = adjb;
  unsigned short* ob2 = Z1T;
  #pragma unroll
  for (int j = 0; j < 4; ++j) {
    const int k = 16 * j + l15;
    #pragma unroll
    for (int r = 0; r < 4; ++r) {
      const int m = 16 * wv + 4 * q + r;
      const int pos = m * 64 + k;
      float vv2 = (acc2[j][r] - mean1) * rstd1 * ln1g[pos] + ln1b[pos];
      ob1[pos] = f2bf(vv2);
    }
  }
  {
    const int f = l15;
    #pragma unroll
    for (int r = 0; r < 4; ++r) {
      const int m = 16 * wv + 4 * q + r;
      const int pos = m * 16 + f;
      float vv2 = (acc3[r] - mean2) * rstd2 * ln2g[pos] + ln2b[pos];
      ob2[pos] = f2bf(vv2);
    }
  }
  __syncthreads();
  {
    const uint4* sp = reinterpret_cast<const uint4*>(ob1);
    uint4* dp = reinterpret_cast<uint4*>(lnadj + (size_t)b * 4096);
    for (int i = tid; i < 512; i += 256) dp[i] = sp[i];
    if (tid < 128)
      reinterpret_cast<uint4*>(lnfeats + (size_t)b * 1024)[tid] =
          reinterpret_cast<const uint4*>(ob2)[tid];
  }
}

// ---------------------------------------------------------------------------
// TAIL kernel (R16, unchanged): fc4 + fc5 + fc6^T transpose in ONE dispatch.
// ---------------------------------------------------------------------------
#define GP 72
__launch_bounds__(256, 2)
__global__ void tail_kernel(const unsigned short* __restrict__ lnadj,
                            const float* __restrict__ fc4w, const float* __restrict__ fc4b,
                            const unsigned short* __restrict__ lnfeats,
                            const float* __restrict__ fc5w, const float* __restrict__ fc5b,
                            const float* __restrict__ fc6w,
                            float* __restrict__ h45,
                            float* __restrict__ wT6)
{
  const int tid = threadIdx.x;
  const int by = blockIdx.y;

  if (by == 8) {
    int idx = blockIdx.x * 256 + tid;
    for (; idx < 64 * 512; idx += 32 * 256) {
      int rr = idx >> 9, cc = idx & 511;
      wT6[cc * 64 + rr] = fc6w[idx];
    }
    return;
  }

  __shared__ __align__(16) unsigned short At[64 * GP];
  __shared__ __align__(16) unsigned short Wt[64 * GP];
  const bool is4 = (by < 4);
  const unsigned short* A = is4 ? lnadj : lnfeats;
  const float* W = is4 ? fc4w : fc5w;
  const float* bias = is4 ? fc4b : fc5b;
  const int K = is4 ? 4096 : 1024;
  const int coff = is4 ? 0 : 256;
  const int m0 = blockIdx.x * 64;
  const int n0 = (is4 ? by : (by - 4)) * 64;
  const int w = tid >> 6, lane = tid & 63;
  const int l15 = lane & 15, q = lane >> 4;
  const int srow = tid >> 2, sko = (tid & 3) * 16;

  f32x4 acc[4];
  #pragma unroll
  for (int j = 0; j < 4; ++j) acc[j] = f32x4{0.f, 0.f, 0.f, 0.f};

  for (int kc = 0; kc < K; kc += 64) {
    __syncthreads();
    {
      const unsigned short* ap = &A[(size_t)(m0 + srow) * K + kc + sko];
      *reinterpret_cast<uint4*>(&At[srow * GP + sko]) =
          *reinterpret_cast<const uint4*>(ap);
      *reinterpret_cast<uint4*>(&At[srow * GP + sko + 8]) =
          *reinterpret_cast<const uint4*>(ap + 8);
      const float* wp = &W[(size_t)(n0 + srow) * K + kc + sko];
      const float4 v0 = reinterpret_cast<const float4*>(wp)[0];
      const float4 v1 = reinterpret_cast<const float4*>(wp)[1];
      const float4 v2 = reinterpret_cast<const float4*>(wp)[2];
      const float4 v3 = reinterpret_cast<const float4*>(wp)[3];
      uint4 o0, o1;
      o0.x = (u32)f2bf(v0.x) | ((u32)f2bf(v0.y) << 16);
      o0.y = (u32)f2bf(v0.z) | ((u32)f2bf(v0.w) << 16);
      o0.z = (u32)f2bf(v1.x) | ((u32)f2bf(v1.y) << 16);
      o0.w = (u32)f2bf(v1.z) | ((u32)f2bf(v1.w) << 16);
      o1.x = (u32)f2bf(v2.x) | ((u32)f2bf(v2.y) << 16);
      o1.y = (u32)f2bf(v2.z) | ((u32)f2bf(v2.w) << 16);
      o1.z = (u32)f2bf(v3.x) | ((u32)f2bf(v3.y) << 16);
      o1.w = (u32)f2bf(v3.z) | ((u32)f2bf(v3.w) << 16);
      *reinterpret_cast<uint4*>(&Wt[srow * GP + sko]) = o0;
      *reinterpret_cast<uint4*>(&Wt[srow * GP + sko + 8]) = o1;
    }
    __syncthreads();
    #pragma unroll
    for (int s = 0; s < 2; ++s) {
      bf16x8 af = ldfrag(&At[(16 * w + l15) * GP + 32 * s + 8 * q]);
      #pragma unroll
      for (int j = 0; j < 4; ++j) {
        bf16x8 bf = ldfrag(&Wt[(16 * j + l15) * GP + 32 * s + 8 * q]);
        acc[j] = __builtin_amdgcn_mfma_f32_16x16x32_bf16(af, bf, acc[j], 0, 0, 0);
      }
    }
  }
  #pragma unroll
  for (int j = 0; j < 4; ++j) {
    const int col = n0 + 16 * j + l15;
    const float bb = bias[col];
    #pragma unroll
    for (int r = 0; r < 4; ++r) {
      const int m = m0 + 16 * w + 4 * q + r;
      h45[(size_t)m * 512 + coff + col] = fmaxf(acc[j][r] + bb, 0.0f);
    }
  }
}

// ---------------------------------------------------------------------------
// Kernel D: unchanged (8 rows/block).
// ---------------------------------------------------------------------------
__launch_bounds__(256)
__global__ void head_kernel(const float* __restrict__ h45,
                            const float* __restrict__ wT6,   // [512][64]
                            const float* __restrict__ b6,
                            const float* __restrict__ w7,    // [10][64]
                            const float* __restrict__ b7,
                            float* __restrict__ out)
{
  __shared__ float row[8][512];
  __shared__ float h6[8][64];
  __shared__ float zb[8][12];
  const int tid = threadIdx.x;
  const int r0 = blockIdx.x * 8;
  for (int i = tid; i < 8 * 128; i += 256) {
    int r = i >> 7, c4 = i & 127;
    *reinterpret_cast<float4*>(&row[r][c4 * 4]) =
        reinterpret_cast<const float4*>(h45 + (size_t)(r0 + r) * 512)[c4];
  }
  __syncthreads();
  const int o = tid & 63, rg = tid >> 6;
  float a0 = b6[o], a1 = a0;
  #pragma unroll 8
  for (int k = 0; k < 512; ++k) {
    float wv = wT6[k * 64 + o];
    a0 += row[rg][k] * wv;
    a1 += row[rg + 4][k] * wv;
  }
  h6[rg][o] = fmaxf(a0, 0.0f);
  h6[rg + 4][o] = fmaxf(a1, 0.0f);
  __syncthreads();
  if (tid < 80) {
    int r = tid / 10, c = tid - r * 10;
    float z = b7[c];
    #pragma unroll
    for (int k = 0; k < 64; ++k) z += h6[r][k] * w7[c * 64 + k];
    zb[r][c] = z;
  }
  __syncthreads();
  if (tid < 80) {
    int r = tid / 10, c = tid - r * 10;
    float mx = zb[r][0];
    #pragma unroll
    for (int j = 1; j < 10; ++j) mx = fmaxf(mx, zb[r][j]);
    float se = 0.f;
    #pragma unroll
    for (int j = 0; j < 10; ++j) se += __expf(zb[r][j] - mx);
    out[(size_t)(r0 + r) * 10 + c] = zb[r][c] - mx - __logf(se);
  }
}

// ---------------------------------------------------------------------------
extern "C" void kernel_launch(void* const* d_in, const int* in_sizes, int n_in,
                              void* d_out, int out_size, void* d_ws, size_t ws_size,
                              hipStream_t stream)
{
  (void)in_sizes; (void)n_in; (void)out_size; (void)ws_size;
  const float* x    = (const float*)d_in[0];
  const float* adj  = (const float*)d_in[1];
  const float* w1   = (const float*)d_in[2];
  const float* w2   = (const float*)d_in[3];
  const float* alpha = (const float*)d_in[4];
  const float* bin_score = (const float*)d_in[5];
  const float* fc2w = (const float*)d_in[6];
  const float* fc2b = (const float*)d_in[7];
  const float* fc3w = (const float*)d_in[8];
  const float* fc3b = (const float*)d_in[9];
  const float* ln1g = (const float*)d_in[10];
  const float* ln1b = (const float*)d_in[11];
  const float* fc4w = (const float*)d_in[12];
  const float* fc4b = (const float*)d_in[13];
  const float* ln2g = (const float*)d_in[14];
  const float* ln2b = (const float*)d_in[15];
  const float* fc5w = (const float*)d_in[16];
  const float* fc5b = (const float*)d_in[17];
  const float* fc6w = (const float*)d_in[18];
  const float* fc6b = (const float*)d_in[19];
  const float* fc7w = (const float*)d_in[20];
  const float* fc7b = (const float*)d_in[21];
  float* out = (float*)d_out;

  char* ws = (char*)d_ws;
  size_t off = 0;
  unsigned short* lnadj = (unsigned short*)(ws + off);  off += (size_t)2048 * 4096 * 2;
  unsigned short* lnfeats = (unsigned short*)(ws + off); off += (size_t)2048 * 1024 * 2;
  float* h45 = (float*)(ws + off);                      off += (size_t)2048 * 512 * 4;
  float* wT6 = (float*)(ws + off);                      off += (size_t)512 * 64 * 4;

  hipLaunchKernelGGL(fused_kernel, dim3(2048), dim3(256), 0, stream,
                     x, adj, w1, w2, alpha, bin_score,
                     fc2w, fc2b, fc3w, fc3b,
                     ln1g, ln1b, ln2g, ln2b, lnadj, lnfeats);
  hipLaunchKernelGGL(tail_kernel, dim3(32, 9), dim3(256), 0, stream,
                     lnadj, fc4w, fc4b, lnfeats, fc5w, fc5b, fc6w, h45, wT6);
  hipLaunchKernelGGL(head_kernel, dim3(256), dim3(256), 0, stream,
                     h45, wT6, fc6b, fc7w, fc7b, out);
}

// Round 20
// 185.959 us; speedup vs baseline: 1.2291x; 1.1220x over previous
//
#include <hip/hip_runtime.h>
#include <hip/hip_bf16.h>
#include <hip/hip_fp16.h>

// Problem constants
#define B_   2048
#define NN   128    // NMAX
#define MM   64     // HN
#define HD_  128
#define IND  18
#define FD_  16

typedef unsigned int u32;
typedef _Float16 h2_t __attribute__((ext_vector_type(2)));
typedef __attribute__((ext_vector_type(8))) short bf16x8;
typedef __attribute__((ext_vector_type(4))) float f32x4;

__device__ __forceinline__ float fdot2f(u32 a, u32 b, float c) {
#if defined(__has_builtin)
#if __has_builtin(__builtin_amdgcn_fdot2)
  return __builtin_amdgcn_fdot2(__builtin_bit_cast(h2_t, a),
                                __builtin_bit_cast(h2_t, b), c, false);
#else
  h2_t x = __builtin_bit_cast(h2_t, a), y = __builtin_bit_cast(h2_t, b);
  return c + (float)x[0] * (float)y[0] + (float)x[1] * (float)y[1];
#endif
#else
  h2_t x = __builtin_bit_cast(h2_t, a), y = __builtin_bit_cast(h2_t, b);
  return c + (float)x[0] * (float)y[0] + (float)x[1] * (float)y[1];
#endif
}

__device__ __forceinline__ u32 pk2(float a, float b) {
#if defined(__has_builtin)
#if __has_builtin(__builtin_amdgcn_cvt_pkrtz)
  return __builtin_bit_cast(u32, __builtin_amdgcn_cvt_pkrtz(a, b));
#else
  __half ha = __float2half_rn(a), hb = __float2half_rn(b);
  return (u32)__half_as_ushort(ha) | ((u32)__half_as_ushort(hb) << 16);
#endif
#else
  __half ha = __float2half_rn(a), hb = __float2half_rn(b);
  return (u32)__half_as_ushort(ha) | ((u32)__half_as_ushort(hb) << 16);
#endif
}

__device__ __forceinline__ float rcpf_(float x) {
#if defined(__has_builtin)
#if __has_builtin(__builtin_amdgcn_rcpf)
  return __builtin_amdgcn_rcpf(x);
#else
  return 1.0f / x;
#endif
#else
  return 1.0f / x;
#endif
}

__device__ __forceinline__ float h_lo(u32 d) {
  return __half2float(__ushort_as_half((unsigned short)(d & 0xffffu)));
}
__device__ __forceinline__ float h_hi(u32 d) {
  return __half2float(__ushort_as_half((unsigned short)(d >> 16)));
}

__device__ __forceinline__ float bf2f(unsigned short u) {
  union { float f; u32 i; } z; z.i = ((u32)u) << 16; return z.f;
}
__device__ __forceinline__ unsigned short f2bf(float f) {
  union { float fv; u32 u; } z; z.fv = f;
  u32 lsb = (z.u >> 16) & 1u;
  return (unsigned short)((z.u + 0x7fffu + lsb) >> 16);
}
__device__ __forceinline__ u32 bfpk(float a, float b) {
  return (u32)f2bf(a) | ((u32)f2bf(b) << 16);
}
__device__ __forceinline__ bf16x8 ldfrag(const unsigned short* p) {
  return __builtin_bit_cast(bf16x8, *reinterpret_cast<const uint4*>(p));
}
__device__ __forceinline__ u32 comb2(u32 ps, u32 pf, float a, float na) {
  float r0 = a * bf2f((unsigned short)(ps & 0xffffu)) + na * bf2f((unsigned short)(pf & 0xffffu));
  float r1 = a * bf2f((unsigned short)(ps >> 16)) + na * bf2f((unsigned short)(pf >> 16));
  return (u32)f2bf(r0) | ((u32)f2bf(r1) << 16);
}

// ---------------------------------------------------------------------------
// FUSED kernel (R20): (256,3) with a register diet to fit the 84-VGPR cap:
//  - Sinkhorn v-pass reads K cols from LDS on the fly (drops kta/ktb, -64 regs)
//  - Phase A streams w A-frags per (at,kt) from L2 (drops wA[4][4], -64 peak)
//  - act computed in two 4-nt halves (acc 32 -> 16 live)
// Everything else identical to R17/R19 (validated bodies).
// ---------------------------------------------------------------------------
#define AP 136   // bf16 row pitch (272 B); 68 dwords

__launch_bounds__(256, 3)
__global__ void fused_kernel(const float* __restrict__ x,
                             const float* __restrict__ adj,
                             const float* __restrict__ w1,
                             const float* __restrict__ w2,
                             const float* __restrict__ alpha_p,
                             const float* __restrict__ bin_score,
                             const float* __restrict__ fc2w, const float* __restrict__ fc2b,
                             const float* __restrict__ fc3w, const float* __restrict__ fc3b,
                             const float* __restrict__ ln1g, const float* __restrict__ ln1b,
                             const float* __restrict__ ln2g, const float* __restrict__ ln2b,
                             unsigned short* __restrict__ lnadj,
                             unsigned short* __restrict__ lnfeats)
{
  __shared__ __align__(16) u32 Ksh[64 * 68];               // 17408 B: K0 -> P0 -> Pc
  __shared__ __align__(16) u32 vhs[2][64];
  __shared__ __align__(16) u32 uhs[2][32];
  __shared__ __align__(16) unsigned short adjb[64 * AP];   // 17408 B: actw / adj halves / xfT / ob1
  __shared__ __align__(16) unsigned short Z1T[64 * AP];    // 17408 B: K1 -> P1 -> Z1 -> ob2
  __shared__ float red[16];

  const int tid = threadIdx.x;
  const int wv = tid >> 6;
  const int lane = tid & 63;
  const int l15 = lane & 15, q = lane >> 4;
  const int b = blockIdx.x;
  u32* K1u = reinterpret_cast<u32*>(Z1T);

  // ======================= Phase A: scores -> K ==========================
  {
    const int sw = wv & 1;               // stream
    const int mtbase = (wv >> 1) * 4;    // slice half
    const float* wm = sw ? w2 : w1;
    const float* fw = sw ? fc3w : fc2w;
    const float* fb = sw ? fc3b : fc2b;
    unsigned short* Kshh = sw ? Z1T : reinterpret_cast<unsigned short*>(Ksh);
    unsigned short* actw = adjb + (size_t)wv * (16 * AP);  // per-wave scratch

    uint4 fcwB[8];
    #pragma unroll
    for (int nt = 0; nt < 8; ++nt) {
      const int ch = 16 * nt + l15;
      uint4 o = make_uint4(0u, 0u, 0u, 0u);
      if (sw) {
        if (q < 2) {
          const float* fr = fw + (size_t)ch * 16 + 8 * q;
          float4 va = *reinterpret_cast<const float4*>(fr);
          float4 vb = *reinterpret_cast<const float4*>(fr + 4);
          o = make_uint4(bfpk(va.x, va.y), bfpk(va.z, va.w),
                         bfpk(vb.x, vb.y), bfpk(vb.z, vb.w));
        }
      } else {
        if (q == 0) o.x = bfpk(fw[ch * 2], fw[ch * 2 + 1]);
      }
      fcwB[nt] = o;
    }
    float bb[8];
    #pragma unroll
    for (int nt = 0; nt < 8; ++nt) bb[nt] = fb[16 * nt + l15];

    #pragma unroll 1
    for (int mi = 0; mi < 4; ++mi) {
      const int mt = mtbase + mi;
      // xa for this slice only (4 regs)
      uint4 xv = make_uint4(0u, 0u, 0u, 0u);
      {
        const int node = 16 * mt + l15;
        const float* xp = x + ((size_t)b * NN + node) * IND + (sw ? 2 : 0);
        if (sw) {
          if (q < 2) {
            float2 p0 = *reinterpret_cast<const float2*>(xp + 8 * q);
            float2 p1 = *reinterpret_cast<const float2*>(xp + 8 * q + 2);
            float2 p2 = *reinterpret_cast<const float2*>(xp + 8 * q + 4);
            float2 p3 = *reinterpret_cast<const float2*>(xp + 8 * q + 6);
            xv = make_uint4(bfpk(p0.x, p0.y), bfpk(p1.x, p1.y),
                            bfpk(p2.x, p2.y), bfpk(p3.x, p3.y));
          }
        } else {
          if (q == 0) {
            float2 p0 = *reinterpret_cast<const float2*>(xp);
            xv.x = bfpk(p0.x, p0.y);
          }
        }
      }
      // act in two halves of 4 nt (acc live = 16 regs)
      #pragma unroll
      for (int hh = 0; hh < 2; ++hh) {
        f32x4 a4[4];
        #pragma unroll
        for (int nt = 0; nt < 4; ++nt)
          a4[nt] = __builtin_amdgcn_mfma_f32_16x16x32_bf16(
              __builtin_bit_cast(bf16x8, xv),
              __builtin_bit_cast(bf16x8, fcwB[4 * hh + nt]),
              f32x4{0.f, 0.f, 0.f, 0.f}, 0, 0, 0);
        #pragma unroll
        for (int nt = 0; nt < 4; ++nt) {
          const int ntg = 4 * hh + nt;
          #pragma unroll
          for (int r = 0; r < 4; ++r) {
            float v = fmaxf(a4[nt][r] + bb[ntg], 0.0f);
            actw[(4 * q + r) * AP + 16 * ntg + l15] = f2bf(v);
          }
        }
      }
      uint4 sB[4];
      #pragma unroll
      for (int kt = 0; kt < 4; ++kt)
        sB[kt] = *reinterpret_cast<const uint4*>(&actw[l15 * AP + 32 * kt + 8 * q]);
      // scores: stream w A-frags from global (L2-resident), remat under cap
      #pragma unroll
      for (int at = 0; at < 4; ++at) {
        const float* wrow = wm + (size_t)(16 * at + l15) * 128;
        f32x4 sa = f32x4{0.f, 0.f, 0.f, 0.f};
        #pragma unroll
        for (int kt = 0; kt < 4; ++kt) {
          float4 va = *reinterpret_cast<const float4*>(wrow + 32 * kt + 8 * q);
          float4 vb = *reinterpret_cast<const float4*>(wrow + 32 * kt + 8 * q + 4);
          uint4 wf = make_uint4(bfpk(va.x, va.y), bfpk(va.z, va.w),
                                bfpk(vb.x, vb.y), bfpk(vb.z, vb.w));
          sa = __builtin_amdgcn_mfma_f32_16x16x32_bf16(
              __builtin_bit_cast(bf16x8, wf), __builtin_bit_cast(bf16x8, sB[kt]),
              sa, 0, 0, 0);
        }
        #pragma unroll
        for (int r = 0; r < 4; ++r) {
          float kv = fminf(__expf(fmaxf(sa[r], 0.0f)), 60000.0f);
          Kshh[(16 * at + 4 * q + r) * AP + 16 * mt + l15] =
              __half_as_ushort(__float2half_rn(kv));
        }
      }
    }
  }
  __syncthreads();   // K0 (Ksh), K1 (Z1T) complete; actw (adjb) dead

  const float ebs = __expf(bin_score[0]);

  // ============== Phase B: Sinkhorn (waves 0-1) | adj h0 (waves 2-3) =====
  if (wv < 2) {
    const int l = lane;
    u32* Ks = (wv == 0) ? Ksh : K1u;
    u32 kr[64];
    #pragma unroll
    for (int t = 0; t < 16; ++t) {
      uint4 kv = *reinterpret_cast<const uint4*>(Ks + l * 68 + 4 * t);
      kr[4 * t + 0] = kv.x; kr[4 * t + 1] = kv.y;
      kr[4 * t + 2] = kv.z; kr[4 * t + 3] = kv.w;
    }

    u32* vh = vhs[wv];
    u32* uh = uhs[wv];
    vh[l] = 0x3C003C00u;
    float v128 = 1.0f, sum_v = 129.0f;
    float u_old = 0.0f, vo0 = 1.0f, vo1 = 1.0f;
    float ur = 0.0f;
    const float TOL = 1.5e-3f;

    for (int it = 0; it < 100; ++it) {
      const float u64v = 128.0f * rcpf_(ebs * sum_v);
      // u-pass: row l (register K)
      float a0 = ebs * v128, a1 = 0.f, a2 = 0.f, a3 = 0.f;
      const uint4* vh4 = reinterpret_cast<const uint4*>(vh);
      #pragma unroll
      for (int t = 0; t < 16; ++t) {
        uint4 vvv = vh4[t];
        a0 = fdot2f(kr[4 * t + 0], vvv.x, a0);
        a1 = fdot2f(kr[4 * t + 1], vvv.y, a1);
        a2 = fdot2f(kr[4 * t + 2], vvv.z, a2);
        a3 = fdot2f(kr[4 * t + 3], vvv.w, a3);
      }
      float urn = rcpf_((a0 + a1) + (a2 + a3));
      float m1 = fabsf(urn - u_old) - TOL * urn;
      u_old = urn; ur = urn;
      float su = urn;
      su += __shfl_xor(su, 1);  su += __shfl_xor(su, 2);
      su += __shfl_xor(su, 4);  su += __shfl_xor(su, 8);
      su += __shfl_xor(su, 16); su += __shfl_xor(su, 32);
      const float sum_u = su + u64v;
      const float v128n = 64.0f * rcpf_(ebs * sum_u);
      float upr = __shfl_xor(urn, 1);
      if (!(l & 1)) uh[l >> 1] = pk2(urn, upr);
      // v-pass: cols 2l,2l+1 — K columns read from LDS on the fly
      float c0a = ebs * u64v, c0b = 0.f, c1a = ebs * u64v, c1b = 0.f;
      #pragma unroll
      for (int j = 0; j < 32; ++j) {
        u32 d0 = Ks[(2 * j) * 68 + l];
        u32 d1 = Ks[(2 * j + 1) * 68 + l];
        u32 ka = (d0 & 0xffffu) | (d1 << 16);
        u32 kb = (d0 >> 16) | (d1 & 0xffff0000u);
        u32 uw = uh[j];
        if (j & 1) { c0b = fdot2f(ka, uw, c0b); c1b = fdot2f(kb, uw, c1b); }
        else       { c0a = fdot2f(ka, uw, c0a); c1a = fdot2f(kb, uw, c1a); }
      }
      float v0n = rcpf_(c0a + c0b);
      float v1n = rcpf_(c1a + c1b);
      float m2 = fabsf(v0n - vo0) - TOL * v0n;
      float m3 = fabsf(v1n - vo1) - TOL * v1n;
      vo0 = v0n; vo1 = v1n;
      vh[l] = pk2(v0n, v1n);
      float sv = v0n + v1n;
      sv += __shfl_xor(sv, 1);  sv += __shfl_xor(sv, 2);
      sv += __shfl_xor(sv, 4);  sv += __shfl_xor(sv, 8);
      sv += __shfl_xor(sv, 16); sv += __shfl_xor(sv, 32);
      sum_v = sv + v128n;
      v128 = v128n;
      float mcond = fmaxf(m1, fmaxf(m2, m3));
      if (__all(mcond <= 0.0f)) break;
    }

    // P = K*u*v (bf16) IN PLACE over Ks
    {
      const uint4* vh4 = reinterpret_cast<const uint4*>(vh);
      #pragma unroll
      for (int t = 0; t < 16; ++t) {
        uint4 vvv = vh4[t];
        u32 o0 = bfpk(h_lo(kr[4 * t + 0]) * ur * h_lo(vvv.x),
                      h_hi(kr[4 * t + 0]) * ur * h_hi(vvv.x));
        u32 o1 = bfpk(h_lo(kr[4 * t + 1]) * ur * h_lo(vvv.y),
                      h_hi(kr[4 * t + 1]) * ur * h_hi(vvv.y));
        u32 o2 = bfpk(h_lo(kr[4 * t + 2]) * ur * h_lo(vvv.z),
                      h_hi(kr[4 * t + 2]) * ur * h_hi(vvv.z));
        u32 o3 = bfpk(h_lo(kr[4 * t + 3]) * ur * h_lo(vvv.w),
                      h_hi(kr[4 * t + 3]) * ur * h_hi(vvv.w));
        *reinterpret_cast<uint4*>(&Ks[l * 68 + 4 * t]) = make_uint4(o0, o1, o2, o3);
      }
    }
  } else {
    // stage adj rows 0..63 -> adjb (128 threads)
    const float4* src = reinterpret_cast<const float4*>(adj + (size_t)b * (NN * NN));
    for (int i = tid - 128; i < 64 * 32; i += 128) {
      int row = i >> 5, c4 = i & 31;
      float4 v = src[i];
      u32 w0 = (u32)f2bf(v.x) | ((u32)f2bf(v.y) << 16);
      u32 w1 = (u32)f2bf(v.z) | ((u32)f2bf(v.w) << 16);
      *reinterpret_cast<uint2*>(&adjb[row * AP + c4 * 4]) = make_uint2(w0, w1);
    }
  }
  __syncthreads();   // P0 (Ksh), P1 (Z1T); adjb h0 staged

  // ======================= Phase C: align ================================
  const float aa = 1.0f / (1.0f + __expf(-alpha_p[0]));
  const float na = 1.0f - aa;
  for (int i = tid; i < 4096; i += 256) {
    int row = i >> 6, cd = i & 63;
    Ksh[row * 68 + cd] = comb2(Ksh[row * 68 + cd], K1u[row * 68 + cd], aa, na);
  }
  __syncthreads();   // Pc ready; P1 (Z1T) dead
  const unsigned short* Pc = reinterpret_cast<const unsigned short*>(Ksh);

  // M1 half 0
  {
    f32x4 acch[4];
    #pragma unroll
    for (int j = 0; j < 4; ++j) acch[j] = f32x4{0.f, 0.f, 0.f, 0.f};
    #pragma unroll
    for (int kt = 0; kt < 4; ++kt) {
      const int d0 = 32 * kt + 8 * q;
      bf16x8 af = ldfrag(&adjb[(16 * wv + l15) * AP + d0]);
      #pragma unroll
      for (int j = 0; j < 4; ++j) {
        bf16x8 bf = ldfrag(&Pc[(16 * j + l15) * AP + d0]);
        acch[j] = __builtin_amdgcn_mfma_f32_16x16x32_bf16(af, bf, acch[j], 0, 0, 0);
      }
    }
    __syncthreads();   // all combine reads of Z1T done block-wide
    #pragma unroll
    for (int j = 0; j < 4; ++j) {
      const int k = 16 * j + l15;
      const int nbase = 16 * wv + 4 * q;
      u32 w0 = (u32)f2bf(acch[j][0]) | ((u32)f2bf(acch[j][1]) << 16);
      u32 w1 = (u32)f2bf(acch[j][2]) | ((u32)f2bf(acch[j][3]) << 16);
      *reinterpret_cast<uint2*>(&Z1T[k * AP + nbase]) = make_uint2(w0, w1);
    }
  }
  __syncthreads();   // adjb h0 reads done

  // stage adj rows 64..127
  {
    const float4* src = reinterpret_cast<const float4*>(
        adj + (size_t)b * (NN * NN) + (size_t)64 * NN);
    for (int i = tid; i < 64 * 32; i += 256) {
      int row = i >> 5, c4 = i & 31;
      float4 v = src[i];
      u32 w0 = (u32)f2bf(v.x) | ((u32)f2bf(v.y) << 16);
      u32 w1 = (u32)f2bf(v.z) | ((u32)f2bf(v.w) << 16);
      *reinterpret_cast<uint2*>(&adjb[row * AP + c4 * 4]) = make_uint2(w0, w1);
    }
  }
  __syncthreads();

  // M1 half 1
  {
    f32x4 acch[4];
    #pragma unroll
    for (int j = 0; j < 4; ++j) acch[j] = f32x4{0.f, 0.f, 0.f, 0.f};
    #pragma unroll
    for (int kt = 0; kt < 4; ++kt) {
      const int d0 = 32 * kt + 8 * q;
      bf16x8 af = ldfrag(&adjb[(16 * wv + l15) * AP + d0]);
      #pragma unroll
      for (int j = 0; j < 4; ++j) {
        bf16x8 bf = ldfrag(&Pc[(16 * j + l15) * AP + d0]);
        acch[j] = __builtin_amdgcn_mfma_f32_16x16x32_bf16(af, bf, acch[j], 0, 0, 0);
      }
    }
    #pragma unroll
    for (int j = 0; j < 4; ++j) {
      const int k = 16 * j + l15;
      const int nbase = 64 + 16 * wv + 4 * q;
      u32 w0 = (u32)f2bf(acch[j][0]) | ((u32)f2bf(acch[j][1]) << 16);
      u32 w1 = (u32)f2bf(acch[j][2]) | ((u32)f2bf(acch[j][3]) << 16);
      *reinterpret_cast<uint2*>(&Z1T[k * AP + nbase]) = make_uint2(w0, w1);
    }
  }
  __syncthreads();   // Z1T complete; adjb free

  // stage xfT into adjb tail
  unsigned short* xfT = adjb + 48 * AP;
  for (int i = tid; i < 2048; i += 256) {
    int n = i & 127, f = i >> 7;
    xfT[f * AP + n] = f2bf(x[((size_t)b * NN + n) * IND + 2 + f]);
  }
  __syncthreads();

  // M2: al2 = Pc @ Z1 ; M3: feats = Pc @ xf
  f32x4 acc2[4];
  f32x4 acc3 = f32x4{0.f, 0.f, 0.f, 0.f};
  #pragma unroll
  for (int j = 0; j < 4; ++j) acc2[j] = f32x4{0.f, 0.f, 0.f, 0.f};
  #pragma unroll
  for (int nt = 0; nt < 4; ++nt) {
    const int n0 = 32 * nt + 8 * q;
    bf16x8 af = ldfrag(&Pc[(16 * wv + l15) * AP + n0]);
    #pragma unroll
    for (int j = 0; j < 4; ++j) {
      bf16x8 bv = ldfrag(&Z1T[(16 * j + l15) * AP + n0]);
      acc2[j] = __builtin_amdgcn_mfma_f32_16x16x32_bf16(af, bv, acc2[j], 0, 0, 0);
    }
    bf16x8 bx = ldfrag(&xfT[l15 * AP + n0]);
    acc3 = __builtin_amdgcn_mfma_f32_16x16x32_bf16(af, bx, acc3, 0, 0, 0);
  }

  // LN reductions
  {
    float s1 = 0.f, q1 = 0.f, s2 = 0.f, q2 = 0.f;
    #pragma unroll
    for (int j = 0; j < 4; ++j)
      #pragma unroll
      for (int r = 0; r < 4; ++r) { float v = acc2[j][r]; s1 += v; q1 += v * v; }
    #pragma unroll
    for (int r = 0; r < 4; ++r) { float v = acc3[r]; s2 += v; q2 += v * v; }
    #pragma unroll
    for (int off = 1; off < 64; off <<= 1) {
      s1 += __shfl_xor(s1, off); q1 += __shfl_xor(q1, off);
      s2 += __shfl_xor(s2, off); q2 += __shfl_xor(q2, off);
    }
    if (lane == 0) { red[wv] = s1; red[4 + wv] = q1; red[8 + wv] = s2; red[12 + wv] = q2; }
  }
  __syncthreads();
  const float S1 = red[0] + red[1] + red[2] + red[3];
  const float Q1 = red[4] + red[5] + red[6] + red[7];
  const float S2 = red[8] + red[9] + red[10] + red[11];
  const float Q2 = red[12] + red[13] + red[14] + red[15];
  const float mean1 = S1 * (1.0f / 4096.0f);
  const float rstd1 = rsqrtf(Q1 * (1.0f / 4096.0f) - mean1 * mean1 + 1e-5f);
  const float mean2 = S2 * (1.0f / 1024.0f);
  const float rstd2 = rsqrtf(Q2 * (1.0f / 1024.0f) - mean2 * mean2 + 1e-5f);

  // normalize + bounce through freed LDS
  unsigned short* ob1 = adjb;
  unsigned short* ob2 = Z1T;
  #pragma unroll
  for (int j = 0; j < 4; ++j) {
    const int k = 16 * j + l15;
    #pragma unroll
    for (int r = 0; r < 4; ++r) {
      const int m = 16 * wv + 4 * q + r;
      const int pos = m * 64 + k;
      float vv2 = (acc2[j][r] - mean1) * rstd1 * ln1g[pos] + ln1b[pos];
      ob1[pos] = f2bf(vv2);
    }
  }
  {
    const int f = l15;
    #pragma unroll
    for (int r = 0; r < 4; ++r) {
      const int m = 16 * wv + 4 * q + r;
      const int pos = m * 16 + f;
      float vv2 = (acc3[r] - mean2) * rstd2 * ln2g[pos] + ln2b[pos];
      ob2[pos] = f2bf(vv2);
    }
  }
  __syncthreads();
  {
    const uint4* sp = reinterpret_cast<const uint4*>(ob1);
    uint4* dp = reinterpret_cast<uint4*>(lnadj + (size_t)b * 4096);
    for (int i = tid; i < 512; i += 256) dp[i] = sp[i];
    if (tid < 128)
      reinterpret_cast<uint4*>(lnfeats + (size_t)b * 1024)[tid] =
          reinterpret_cast<const uint4*>(ob2)[tid];
  }
}

// ---------------------------------------------------------------------------
// TAIL kernel (R16, unchanged): fc4 + fc5 + fc6^T transpose in ONE dispatch.
// ---------------------------------------------------------------------------
#define GP 72
__launch_bounds__(256, 2)
__global__ void tail_kernel(const unsigned short* __restrict__ lnadj,
                            const float* __restrict__ fc4w, const float* __restrict__ fc4b,
                            const unsigned short* __restrict__ lnfeats,
                            const float* __restrict__ fc5w, const float* __restrict__ fc5b,
                            const float* __restrict__ fc6w,
                            float* __restrict__ h45,
                            float* __restrict__ wT6)
{
  const int tid = threadIdx.x;
  const int by = blockIdx.y;

  if (by == 8) {
    int idx = blockIdx.x * 256 + tid;
    for (; idx < 64 * 512; idx += 32 * 256) {
      int rr = idx >> 9, cc = idx & 511;
      wT6[cc * 64 + rr] = fc6w[idx];
    }
    return;
  }

  __shared__ __align__(16) unsigned short At[64 * GP];
  __shared__ __align__(16) unsigned short Wt[64 * GP];
  const bool is4 = (by < 4);
  const unsigned short* A = is4 ? lnadj : lnfeats;
  const float* W = is4 ? fc4w : fc5w;
  const float* bias = is4 ? fc4b : fc5b;
  const int K = is4 ? 4096 : 1024;
  const int coff = is4 ? 0 : 256;
  const int m0 = blockIdx.x * 64;
  const int n0 = (is4 ? by : (by - 4)) * 64;
  const int w = tid >> 6, lane = tid & 63;
  const int l15 = lane & 15, q = lane >> 4;
  const int srow = tid >> 2, sko = (tid & 3) * 16;

  f32x4 acc[4];
  #pragma unroll
  for (int j = 0; j < 4; ++j) acc[j] = f32x4{0.f, 0.f, 0.f, 0.f};

  for (int kc = 0; kc < K; kc += 64) {
    __syncthreads();
    {
      const unsigned short* ap = &A[(size_t)(m0 + srow) * K + kc + sko];
      *reinterpret_cast<uint4*>(&At[srow * GP + sko]) =
          *reinterpret_cast<const uint4*>(ap);
      *reinterpret_cast<uint4*>(&At[srow * GP + sko + 8]) =
          *reinterpret_cast<const uint4*>(ap + 8);
      const float* wp = &W[(size_t)(n0 + srow) * K + kc + sko];
      const float4 v0 = reinterpret_cast<const float4*>(wp)[0];
      const float4 v1 = reinterpret_cast<const float4*>(wp)[1];
      const float4 v2 = reinterpret_cast<const float4*>(wp)[2];
      const float4 v3 = reinterpret_cast<const float4*>(wp)[3];
      uint4 o0, o1;
      o0.x = (u32)f2bf(v0.x) | ((u32)f2bf(v0.y) << 16);
      o0.y = (u32)f2bf(v0.z) | ((u32)f2bf(v0.w) << 16);
      o0.z = (u32)f2bf(v1.x) | ((u32)f2bf(v1.y) << 16);
      o0.w = (u32)f2bf(v1.z) | ((u32)f2bf(v1.w) << 16);
      o1.x = (u32)f2bf(v2.x) | ((u32)f2bf(v2.y) << 16);
      o1.y = (u32)f2bf(v2.z) | ((u32)f2bf(v2.w) << 16);
      o1.z = (u32)f2bf(v3.x) | ((u32)f2bf(v3.y) << 16);
      o1.w = (u32)f2bf(v3.z) | ((u32)f2bf(v3.w) << 16);
      *reinterpret_cast<uint4*>(&Wt[srow * GP + sko]) = o0;
      *reinterpret_cast<uint4*>(&Wt[srow * GP + sko + 8]) = o1;
    }
    __syncthreads();
    #pragma unroll
    for (int s = 0; s < 2; ++s) {
      bf16x8 af = ldfrag(&At[(16 * w + l15) * GP + 32 * s + 8 * q]);
      #pragma unroll
      for (int j = 0; j < 4; ++j) {
        bf16x8 bf = ldfrag(&Wt[(16 * j + l15) * GP + 32 * s + 8 * q]);
        acc[j] = __builtin_amdgcn_mfma_f32_16x16x32_bf16(af, bf, acc[j], 0, 0, 0);
      }
    }
  }
  #pragma unroll
  for (int j = 0; j < 4; ++j) {
    const int col = n0 + 16 * j + l15;
    const float bb = bias[col];
    #pragma unroll
    for (int r = 0; r < 4; ++r) {
      const int m = m0 + 16 * w + 4 * q + r;
      h45[(size_t)m * 512 + coff + col] = fmaxf(acc[j][r] + bb, 0.0f);
    }
  }
}

// ---------------------------------------------------------------------------
// Kernel D: unchanged (8 rows/block).
// ---------------------------------------------------------------------------
__launch_bounds__(256)
__global__ void head_kernel(const float* __restrict__ h45,
                            const float* __restrict__ wT6,   // [512][64]
                            const float* __restrict__ b6,
                            const float* __restrict__ w7,    // [10][64]
                            const float* __restrict__ b7,
                            float* __restrict__ out)
{
  __shared__ float row[8][512];
  __shared__ float h6[8][64];
  __shared__ float zb[8][12];
  const int tid = threadIdx.x;
  const int r0 = blockIdx.x * 8;
  for (int i = tid; i < 8 * 128; i += 256) {
    int r = i >> 7, c4 = i & 127;
    *reinterpret_cast<float4*>(&row[r][c4 * 4]) =
        reinterpret_cast<const float4*>(h45 + (size_t)(r0 + r) * 512)[c4];
  }
  __syncthreads();
  const int o = tid & 63, rg = tid >> 6;
  float a0 = b6[o], a1 = a0;
  #pragma unroll 8
  for (int k = 0; k < 512; ++k) {
    float wv = wT6[k * 64 + o];
    a0 += row[rg][k] * wv;
    a1 += row[rg + 4][k] * wv;
  }
  h6[rg][o] = fmaxf(a0, 0.0f);
  h6[rg + 4][o] = fmaxf(a1, 0.0f);
  __syncthreads();
  if (tid < 80) {
    int r = tid / 10, c = tid - r * 10;
    float z = b7[c];
    #pragma unroll
    for (int k = 0; k < 64; ++k) z += h6[r][k] * w7[c * 64 + k];
    zb[r][c] = z;
  }
  __syncthreads();
  if (tid < 80) {
    int r = tid / 10, c = tid - r * 10;
    float mx = zb[r][0];
    #pragma unroll
    for (int j = 1; j < 10; ++j) mx = fmaxf(mx, zb[r][j]);
    float se = 0.f;
    #pragma unroll
    for (int j = 0; j < 10; ++j) se += __expf(zb[r][j] - mx);
    out[(size_t)(r0 + r) * 10 + c] = zb[r][c] - mx - __logf(se);
  }
}

// ---------------------------------------------------------------------------
extern "C" void kernel_launch(void* const* d_in, const int* in_sizes, int n_in,
                              void* d_out, int out_size, void* d_ws, size_t ws_size,
                              hipStream_t stream)
{
  (void)in_sizes; (void)n_in; (void)out_size; (void)ws_size;
  const float* x    = (const float*)d_in[0];
  const float* adj  = (const float*)d_in[1];
  const float* w1   = (const float*)d_in[2];
  const float* w2   = (const float*)d_in[3];
  const float* alpha = (const float*)d_in[4];
  const float* bin_score = (const float*)d_in[5];
  const float* fc2w = (const float*)d_in[6];
  const float* fc2b = (const float*)d_in[7];
  const float* fc3w = (const float*)d_in[8];
  const float* fc3b = (const float*)d_in[9];
  const float* ln1g = (const float*)d_in[10];
  const float* ln1b = (const float*)d_in[11];
  const float* fc4w = (const float*)d_in[12];
  const float* fc4b = (const float*)d_in[13];
  const float* ln2g = (const float*)d_in[14];
  const float* ln2b = (const float*)d_in[15];
  const float* fc5w = (const float*)d_in[16];
  const float* fc5b = (const float*)d_in[17];
  const float* fc6w = (const float*)d_in[18];
  const float* fc6b = (const float*)d_in[19];
  const float* fc7w = (const float*)d_in[20];
  const float* fc7b = (const float*)d_in[21];
  float* out = (float*)d_out;

  char* ws = (char*)d_ws;
  size_t off = 0;
  unsigned short* lnadj = (unsigned short*)(ws + off);  off += (size_t)2048 * 4096 * 2;
  unsigned short* lnfeats = (unsigned short*)(ws + off); off += (size_t)2048 * 1024 * 2;
  float* h45 = (float*)(ws + off);                      off += (size_t)2048 * 512 * 4;
  float* wT6 = (float*)(ws + off);                      off += (size_t)512 * 64 * 4;

  hipLaunchKernelGGL(fused_kernel, dim3(2048), dim3(256), 0, stream,
                     x, adj, w1, w2, alpha, bin_score,
                     fc2w, fc2b, fc3w, fc3b,
                     ln1g, ln1b, ln2g, ln2b, lnadj, lnfeats);
  hipLaunchKernelGGL(tail_kernel, dim3(32, 9), dim3(256), 0, stream,
                     lnadj, fc4w, fc4b, lnfeats, fc5w, fc5b, fc6w, h45, wT6);
  hipLaunchKernelGGL(head_kernel, dim3(256), dim3(256), 0, stream,
                     h45, wT6, fc6b, fc7w, fc7b, out);
}

// Round 21
// 185.648 us; speedup vs baseline: 1.2312x; 1.0017x over previous
//
#include <hip/hip_runtime.h>
#include <hip/hip_bf16.h>
#include <hip/hip_fp16.h>

// Problem constants
#define B_   2048
#define NN   128    // NMAX
#define MM   64     // HN
#define HD_  128
#define IND  18
#define FD_  16

typedef unsigned int u32;
typedef _Float16 h2_t __attribute__((ext_vector_type(2)));
typedef __attribute__((ext_vector_type(8))) short bf16x8;
typedef __attribute__((ext_vector_type(4))) float f32x4;

__device__ __forceinline__ float fdot2f(u32 a, u32 b, float c) {
#if defined(__has_builtin)
#if __has_builtin(__builtin_amdgcn_fdot2)
  return __builtin_amdgcn_fdot2(__builtin_bit_cast(h2_t, a),
                                __builtin_bit_cast(h2_t, b), c, false);
#else
  h2_t x = __builtin_bit_cast(h2_t, a), y = __builtin_bit_cast(h2_t, b);
  return c + (float)x[0] * (float)y[0] + (float)x[1] * (float)y[1];
#endif
#else
  h2_t x = __builtin_bit_cast(h2_t, a), y = __builtin_bit_cast(h2_t, b);
  return c + (float)x[0] * (float)y[0] + (float)x[1] * (float)y[1];
#endif
}

__device__ __forceinline__ u32 pk2(float a, float b) {
#if defined(__has_builtin)
#if __has_builtin(__builtin_amdgcn_cvt_pkrtz)
  return __builtin_bit_cast(u32, __builtin_amdgcn_cvt_pkrtz(a, b));
#else
  __half ha = __float2half_rn(a), hb = __float2half_rn(b);
  return (u32)__half_as_ushort(ha) | ((u32)__half_as_ushort(hb) << 16);
#endif
#else
  __half ha = __float2half_rn(a), hb = __float2half_rn(b);
  return (u32)__half_as_ushort(ha) | ((u32)__half_as_ushort(hb) << 16);
#endif
}

__device__ __forceinline__ float rcpf_(float x) {
#if defined(__has_builtin)
#if __has_builtin(__builtin_amdgcn_rcpf)
  return __builtin_amdgcn_rcpf(x);
#else
  return 1.0f / x;
#endif
#else
  return 1.0f / x;
#endif
}

__device__ __forceinline__ float h_lo(u32 d) {
  return __half2float(__ushort_as_half((unsigned short)(d & 0xffffu)));
}
__device__ __forceinline__ float h_hi(u32 d) {
  return __half2float(__ushort_as_half((unsigned short)(d >> 16)));
}

__device__ __forceinline__ float bf2f(unsigned short u) {
  union { float f; u32 i; } z; z.i = ((u32)u) << 16; return z.f;
}
__device__ __forceinline__ unsigned short f2bf(float f) {
  union { float fv; u32 u; } z; z.fv = f;
  u32 lsb = (z.u >> 16) & 1u;
  return (unsigned short)((z.u + 0x7fffu + lsb) >> 16);
}
__device__ __forceinline__ u32 bfpk(float a, float b) {
  return (u32)f2bf(a) | ((u32)f2bf(b) << 16);
}
__device__ __forceinline__ bf16x8 ldfrag(const unsigned short* p) {
  return __builtin_bit_cast(bf16x8, *reinterpret_cast<const uint4*>(p));
}
__device__ __forceinline__ u32 comb2(u32 ps, u32 pf, float a, float na) {
  float r0 = a * bf2f((unsigned short)(ps & 0xffffu)) + na * bf2f((unsigned short)(pf & 0xffffu));
  float r1 = a * bf2f((unsigned short)(ps >> 16)) + na * bf2f((unsigned short)(pf >> 16));
  return (u32)f2bf(r0) | ((u32)f2bf(r1) << 16);
}

// ---------------------------------------------------------------------------
// FUSED kernel (R21 = R20 + 8 converter blocks appended to the grid).
// Blocks 0..2047: R20's validated OT+align (84 VGPR, 53KB LDS, 3 blk/CU).
// Blocks 2048..2055: convert fc4w/fc5w f32->bf16 into ws + fc6 transpose,
// then return (no barriers touched). They run in the ragged last scheduling
// round (512/768 slots used) => zero added wall time.
// ---------------------------------------------------------------------------
#define AP 136   // bf16 row pitch (272 B); 68 dwords

__launch_bounds__(256, 3)
__global__ void fused_kernel(const float* __restrict__ x,
                             const float* __restrict__ adj,
                             const float* __restrict__ w1,
                             const float* __restrict__ w2,
                             const float* __restrict__ alpha_p,
                             const float* __restrict__ bin_score,
                             const float* __restrict__ fc2w, const float* __restrict__ fc2b,
                             const float* __restrict__ fc3w, const float* __restrict__ fc3b,
                             const float* __restrict__ ln1g, const float* __restrict__ ln1b,
                             const float* __restrict__ ln2g, const float* __restrict__ ln2b,
                             const float* __restrict__ fc4w_g,
                             const float* __restrict__ fc5w_g,
                             const float* __restrict__ fc6w_g,
                             unsigned short* __restrict__ w4b,
                             unsigned short* __restrict__ w5b,
                             float* __restrict__ wT6,
                             unsigned short* __restrict__ lnadj,
                             unsigned short* __restrict__ lnfeats)
{
  const int tid = threadIdx.x;
  const int b = blockIdx.x;

  if (b >= B_) {
    // -------- converter blocks (no LDS use, no barriers) --------
    const int ct = (b - B_) * 256 + tid;   // 0..2047
    {
      const float4* s4 = reinterpret_cast<const float4*>(fc4w_g);
      uint2* d4 = reinterpret_cast<uint2*>(w4b);
      for (int i = ct; i < 256 * 4096 / 4; i += 2048) {
        float4 v = s4[i];
        d4[i] = make_uint2(bfpk(v.x, v.y), bfpk(v.z, v.w));
      }
    }
    {
      const float4* s5 = reinterpret_cast<const float4*>(fc5w_g);
      uint2* d5 = reinterpret_cast<uint2*>(w5b);
      for (int i = ct; i < 256 * 1024 / 4; i += 2048) {
        float4 v = s5[i];
        d5[i] = make_uint2(bfpk(v.x, v.y), bfpk(v.z, v.w));
      }
    }
    for (int i = ct; i < 64 * 512; i += 2048) {
      int rr = i >> 9, cc = i & 511;
      wT6[cc * 64 + rr] = fc6w_g[i];
    }
    return;
  }

  __shared__ __align__(16) u32 Ksh[64 * 68];               // 17408 B: K0 -> P0 -> Pc
  __shared__ __align__(16) u32 vhs[2][64];
  __shared__ __align__(16) u32 uhs[2][32];
  __shared__ __align__(16) unsigned short adjb[64 * AP];   // actw / adj halves / xfT / ob1
  __shared__ __align__(16) unsigned short Z1T[64 * AP];    // K1 -> P1 -> Z1 -> ob2
  __shared__ float red[16];

  const int wv = tid >> 6;
  const int lane = tid & 63;
  const int l15 = lane & 15, q = lane >> 4;
  u32* K1u = reinterpret_cast<u32*>(Z1T);

  // ======================= Phase A: scores -> K ==========================
  {
    const int sw = wv & 1;               // stream
    const int mtbase = (wv >> 1) * 4;    // slice half
    const float* wm = sw ? w2 : w1;
    const float* fw = sw ? fc3w : fc2w;
    const float* fb = sw ? fc3b : fc2b;
    unsigned short* Kshh = sw ? Z1T : reinterpret_cast<unsigned short*>(Ksh);
    unsigned short* actw = adjb + (size_t)wv * (16 * AP);  // per-wave scratch

    uint4 fcwB[8];
    #pragma unroll
    for (int nt = 0; nt < 8; ++nt) {
      const int ch = 16 * nt + l15;
      uint4 o = make_uint4(0u, 0u, 0u, 0u);
      if (sw) {
        if (q < 2) {
          const float* fr = fw + (size_t)ch * 16 + 8 * q;
          float4 va = *reinterpret_cast<const float4*>(fr);
          float4 vb = *reinterpret_cast<const float4*>(fr + 4);
          o = make_uint4(bfpk(va.x, va.y), bfpk(va.z, va.w),
                         bfpk(vb.x, vb.y), bfpk(vb.z, vb.w));
        }
      } else {
        if (q == 0) o.x = bfpk(fw[ch * 2], fw[ch * 2 + 1]);
      }
      fcwB[nt] = o;
    }
    float bb[8];
    #pragma unroll
    for (int nt = 0; nt < 8; ++nt) bb[nt] = fb[16 * nt + l15];

    #pragma unroll 1
    for (int mi = 0; mi < 4; ++mi) {
      const int mt = mtbase + mi;
      uint4 xv = make_uint4(0u, 0u, 0u, 0u);
      {
        const int node = 16 * mt + l15;
        const float* xp = x + ((size_t)b * NN + node) * IND + (sw ? 2 : 0);
        if (sw) {
          if (q < 2) {
            float2 p0 = *reinterpret_cast<const float2*>(xp + 8 * q);
            float2 p1 = *reinterpret_cast<const float2*>(xp + 8 * q + 2);
            float2 p2 = *reinterpret_cast<const float2*>(xp + 8 * q + 4);
            float2 p3 = *reinterpret_cast<const float2*>(xp + 8 * q + 6);
            xv = make_uint4(bfpk(p0.x, p0.y), bfpk(p1.x, p1.y),
                            bfpk(p2.x, p2.y), bfpk(p3.x, p3.y));
          }
        } else {
          if (q == 0) {
            float2 p0 = *reinterpret_cast<const float2*>(xp);
            xv.x = bfpk(p0.x, p0.y);
          }
        }
      }
      #pragma unroll
      for (int hh = 0; hh < 2; ++hh) {
        f32x4 a4[4];
        #pragma unroll
        for (int nt = 0; nt < 4; ++nt)
          a4[nt] = __builtin_amdgcn_mfma_f32_16x16x32_bf16(
              __builtin_bit_cast(bf16x8, xv),
              __builtin_bit_cast(bf16x8, fcwB[4 * hh + nt]),
              f32x4{0.f, 0.f, 0.f, 0.f}, 0, 0, 0);
        #pragma unroll
        for (int nt = 0; nt < 4; ++nt) {
          const int ntg = 4 * hh + nt;
          #pragma unroll
          for (int r = 0; r < 4; ++r) {
            float v = fmaxf(a4[nt][r] + bb[ntg], 0.0f);
            actw[(4 * q + r) * AP + 16 * ntg + l15] = f2bf(v);
          }
        }
      }
      uint4 sB[4];
      #pragma unroll
      for (int kt = 0; kt < 4; ++kt)
        sB[kt] = *reinterpret_cast<const uint4*>(&actw[l15 * AP + 32 * kt + 8 * q]);
      #pragma unroll
      for (int at = 0; at < 4; ++at) {
        const float* wrow = wm + (size_t)(16 * at + l15) * 128;
        f32x4 sa = f32x4{0.f, 0.f, 0.f, 0.f};
        #pragma unroll
        for (int kt = 0; kt < 4; ++kt) {
          float4 va = *reinterpret_cast<const float4*>(wrow + 32 * kt + 8 * q);
          float4 vb = *reinterpret_cast<const float4*>(wrow + 32 * kt + 8 * q + 4);
          uint4 wf = make_uint4(bfpk(va.x, va.y), bfpk(va.z, va.w),
                                bfpk(vb.x, vb.y), bfpk(vb.z, vb.w));
          sa = __builtin_amdgcn_mfma_f32_16x16x32_bf16(
              __builtin_bit_cast(bf16x8, wf), __builtin_bit_cast(bf16x8, sB[kt]),
              sa, 0, 0, 0);
        }
        #pragma unroll
        for (int r = 0; r < 4; ++r) {
          float kv = fminf(__expf(fmaxf(sa[r], 0.0f)), 60000.0f);
          Kshh[(16 * at + 4 * q + r) * AP + 16 * mt + l15] =
              __half_as_ushort(__float2half_rn(kv));
        }
      }
    }
  }
  __syncthreads();   // K0 (Ksh), K1 (Z1T) complete; actw (adjb) dead

  const float ebs = __expf(bin_score[0]);

  // ============== Phase B: Sinkhorn (waves 0-1) | adj h0 (waves 2-3) =====
  if (wv < 2) {
    const int l = lane;
    u32* Ks = (wv == 0) ? Ksh : K1u;
    u32 kr[64];
    #pragma unroll
    for (int t = 0; t < 16; ++t) {
      uint4 kv = *reinterpret_cast<const uint4*>(Ks + l * 68 + 4 * t);
      kr[4 * t + 0] = kv.x; kr[4 * t + 1] = kv.y;
      kr[4 * t + 2] = kv.z; kr[4 * t + 3] = kv.w;
    }

    u32* vh = vhs[wv];
    u32* uh = uhs[wv];
    vh[l] = 0x3C003C00u;
    float v128 = 1.0f, sum_v = 129.0f;
    float u_old = 0.0f, vo0 = 1.0f, vo1 = 1.0f;
    float ur = 0.0f;
    const float TOL = 1.5e-3f;

    for (int it = 0; it < 100; ++it) {
      const float u64v = 128.0f * rcpf_(ebs * sum_v);
      float a0 = ebs * v128, a1 = 0.f, a2 = 0.f, a3 = 0.f;
      const uint4* vh4 = reinterpret_cast<const uint4*>(vh);
      #pragma unroll
      for (int t = 0; t < 16; ++t) {
        uint4 vvv = vh4[t];
        a0 = fdot2f(kr[4 * t + 0], vvv.x, a0);
        a1 = fdot2f(kr[4 * t + 1], vvv.y, a1);
        a2 = fdot2f(kr[4 * t + 2], vvv.z, a2);
        a3 = fdot2f(kr[4 * t + 3], vvv.w, a3);
      }
      float urn = rcpf_((a0 + a1) + (a2 + a3));
      float m1 = fabsf(urn - u_old) - TOL * urn;
      u_old = urn; ur = urn;
      float su = urn;
      su += __shfl_xor(su, 1);  su += __shfl_xor(su, 2);
      su += __shfl_xor(su, 4);  su += __shfl_xor(su, 8);
      su += __shfl_xor(su, 16); su += __shfl_xor(su, 32);
      const float sum_u = su + u64v;
      const float v128n = 64.0f * rcpf_(ebs * sum_u);
      float upr = __shfl_xor(urn, 1);
      if (!(l & 1)) uh[l >> 1] = pk2(urn, upr);
      float c0a = ebs * u64v, c0b = 0.f, c1a = ebs * u64v, c1b = 0.f;
      #pragma unroll
      for (int j = 0; j < 32; ++j) {
        u32 d0 = Ks[(2 * j) * 68 + l];
        u32 d1 = Ks[(2 * j + 1) * 68 + l];
        u32 ka = (d0 & 0xffffu) | (d1 << 16);
        u32 kb = (d0 >> 16) | (d1 & 0xffff0000u);
        u32 uw = uh[j];
        if (j & 1) { c0b = fdot2f(ka, uw, c0b); c1b = fdot2f(kb, uw, c1b); }
        else       { c0a = fdot2f(ka, uw, c0a); c1a = fdot2f(kb, uw, c1a); }
      }
      float v0n = rcpf_(c0a + c0b);
      float v1n = rcpf_(c1a + c1b);
      float m2 = fabsf(v0n - vo0) - TOL * v0n;
      float m3 = fabsf(v1n - vo1) - TOL * v1n;
      vo0 = v0n; vo1 = v1n;
      vh[l] = pk2(v0n, v1n);
      float sv = v0n + v1n;
      sv += __shfl_xor(sv, 1);  sv += __shfl_xor(sv, 2);
      sv += __shfl_xor(sv, 4);  sv += __shfl_xor(sv, 8);
      sv += __shfl_xor(sv, 16); sv += __shfl_xor(sv, 32);
      sum_v = sv + v128n;
      v128 = v128n;
      float mcond = fmaxf(m1, fmaxf(m2, m3));
      if (__all(mcond <= 0.0f)) break;
    }

    // P = K*u*v (bf16) IN PLACE over Ks
    {
      const uint4* vh4 = reinterpret_cast<const uint4*>(vh);
      #pragma unroll
      for (int t = 0; t < 16; ++t) {
        uint4 vvv = vh4[t];
        u32 o0 = bfpk(h_lo(kr[4 * t + 0]) * ur * h_lo(vvv.x),
                      h_hi(kr[4 * t + 0]) * ur * h_hi(vvv.x));
        u32 o1 = bfpk(h_lo(kr[4 * t + 1]) * ur * h_lo(vvv.y),
                      h_hi(kr[4 * t + 1]) * ur * h_hi(vvv.y));
        u32 o2 = bfpk(h_lo(kr[4 * t + 2]) * ur * h_lo(vvv.z),
                      h_hi(kr[4 * t + 2]) * ur * h_hi(vvv.z));
        u32 o3 = bfpk(h_lo(kr[4 * t + 3]) * ur * h_lo(vvv.w),
                      h_hi(kr[4 * t + 3]) * ur * h_hi(vvv.w));
        *reinterpret_cast<uint4*>(&Ks[l * 68 + 4 * t]) = make_uint4(o0, o1, o2, o3);
      }
    }
  } else {
    // stage adj rows 0..63 -> adjb (128 threads)
    const float4* src = reinterpret_cast<const float4*>(adj + (size_t)b * (NN * NN));
    for (int i = tid - 128; i < 64 * 32; i += 128) {
      int row = i >> 5, c4 = i & 31;
      float4 v = src[i];
      u32 w0 = (u32)f2bf(v.x) | ((u32)f2bf(v.y) << 16);
      u32 w1 = (u32)f2bf(v.z) | ((u32)f2bf(v.w) << 16);
      *reinterpret_cast<uint2*>(&adjb[row * AP + c4 * 4]) = make_uint2(w0, w1);
    }
  }
  __syncthreads();   // P0 (Ksh), P1 (Z1T); adjb h0 staged

  // ======================= Phase C: align ================================
  const float aa = 1.0f / (1.0f + __expf(-alpha_p[0]));
  const float na = 1.0f - aa;
  for (int i = tid; i < 4096; i += 256) {
    int row = i >> 6, cd = i & 63;
    Ksh[row * 68 + cd] = comb2(Ksh[row * 68 + cd], K1u[row * 68 + cd], aa, na);
  }
  __syncthreads();   // Pc ready; P1 (Z1T) dead
  const unsigned short* Pc = reinterpret_cast<const unsigned short*>(Ksh);

  // M1 half 0
  {
    f32x4 acch[4];
    #pragma unroll
    for (int j = 0; j < 4; ++j) acch[j] = f32x4{0.f, 0.f, 0.f, 0.f};
    #pragma unroll
    for (int kt = 0; kt < 4; ++kt) {
      const int d0 = 32 * kt + 8 * q;
      bf16x8 af = ldfrag(&adjb[(16 * wv + l15) * AP + d0]);
      #pragma unroll
      for (int j = 0; j < 4; ++j) {
        bf16x8 bf = ldfrag(&Pc[(16 * j + l15) * AP + d0]);
        acch[j] = __builtin_amdgcn_mfma_f32_16x16x32_bf16(af, bf, acch[j], 0, 0, 0);
      }
    }
    __syncthreads();
    #pragma unroll
    for (int j = 0; j < 4; ++j) {
      const int k = 16 * j + l15;
      const int nbase = 16 * wv + 4 * q;
      u32 w0 = (u32)f2bf(acch[j][0]) | ((u32)f2bf(acch[j][1]) << 16);
      u32 w1 = (u32)f2bf(acch[j][2]) | ((u32)f2bf(acch[j][3]) << 16);
      *reinterpret_cast<uint2*>(&Z1T[k * AP + nbase]) = make_uint2(w0, w1);
    }
  }
  __syncthreads();   // adjb h0 reads done

  // stage adj rows 64..127
  {
    const float4* src = reinterpret_cast<const float4*>(
        adj + (size_t)b * (NN * NN) + (size_t)64 * NN);
    for (int i = tid; i < 64 * 32; i += 256) {
      int row = i >> 5, c4 = i & 31;
      float4 v = src[i];
      u32 w0 = (u32)f2bf(v.x) | ((u32)f2bf(v.y) << 16);
      u32 w1 = (u32)f2bf(v.z) | ((u32)f2bf(v.w) << 16);
      *reinterpret_cast<uint2*>(&adjb[row * AP + c4 * 4]) = make_uint2(w0, w1);
    }
  }
  __syncthreads();

  // M1 half 1
  {
    f32x4 acch[4];
    #pragma unroll
    for (int j = 0; j < 4; ++j) acch[j] = f32x4{0.f, 0.f, 0.f, 0.f};
    #pragma unroll
    for (int kt = 0; kt < 4; ++kt) {
      const int d0 = 32 * kt + 8 * q;
      bf16x8 af = ldfrag(&adjb[(16 * wv + l15) * AP + d0]);
      #pragma unroll
      for (int j = 0; j < 4; ++j) {
        bf16x8 bf = ldfrag(&Pc[(16 * j + l15) * AP + d0]);
        acch[j] = __builtin_amdgcn_mfma_f32_16x16x32_bf16(af, bf, acch[j], 0, 0, 0);
      }
    }
    #pragma unroll
    for (int j = 0; j < 4; ++j) {
      const int k = 16 * j + l15;
      const int nbase = 64 + 16 * wv + 4 * q;
      u32 w0 = (u32)f2bf(acch[j][0]) | ((u32)f2bf(acch[j][1]) << 16);
      u32 w1 = (u32)f2bf(acch[j][2]) | ((u32)f2bf(acch[j][3]) << 16);
      *reinterpret_cast<uint2*>(&Z1T[k * AP + nbase]) = make_uint2(w0, w1);
    }
  }
  __syncthreads();   // Z1T complete; adjb free

  // stage xfT into adjb tail
  unsigned short* xfT = adjb + 48 * AP;
  for (int i = tid; i < 2048; i += 256) {
    int n = i & 127, f = i >> 7;
    xfT[f * AP + n] = f2bf(x[((size_t)b * NN + n) * IND + 2 + f]);
  }
  __syncthreads();

  // M2: al2 = Pc @ Z1 ; M3: feats = Pc @ xf
  f32x4 acc2[4];
  f32x4 acc3 = f32x4{0.f, 0.f, 0.f, 0.f};
  #pragma unroll
  for (int j = 0; j < 4; ++j) acc2[j] = f32x4{0.f, 0.f, 0.f, 0.f};
  #pragma unroll
  for (int nt = 0; nt < 4; ++nt) {
    const int n0 = 32 * nt + 8 * q;
    bf16x8 af = ldfrag(&Pc[(16 * wv + l15) * AP + n0]);
    #pragma unroll
    for (int j = 0; j < 4; ++j) {
      bf16x8 bv = ldfrag(&Z1T[(16 * j + l15) * AP + n0]);
      acc2[j] = __builtin_amdgcn_mfma_f32_16x16x32_bf16(af, bv, acc2[j], 0, 0, 0);
    }
    bf16x8 bx = ldfrag(&xfT[l15 * AP + n0]);
    acc3 = __builtin_amdgcn_mfma_f32_16x16x32_bf16(af, bx, acc3, 0, 0, 0);
  }

  // LN reductions
  {
    float s1 = 0.f, q1 = 0.f, s2 = 0.f, q2 = 0.f;
    #pragma unroll
    for (int j = 0; j < 4; ++j)
      #pragma unroll
      for (int r = 0; r < 4; ++r) { float v = acc2[j][r]; s1 += v; q1 += v * v; }
    #pragma unroll
    for (int r = 0; r < 4; ++r) { float v = acc3[r]; s2 += v; q2 += v * v; }
    #pragma unroll
    for (int off = 1; off < 64; off <<= 1) {
      s1 += __shfl_xor(s1, off); q1 += __shfl_xor(q1, off);
      s2 += __shfl_xor(s2, off); q2 += __shfl_xor(q2, off);
    }
    if (lane == 0) { red[wv] = s1; red[4 + wv] = q1; red[8 + wv] = s2; red[12 + wv] = q2; }
  }
  __syncthreads();
  const float S1 = red[0] + red[1] + red[2] + red[3];
  const float Q1 = red[4] + red[5] + red[6] + red[7];
  const float S2 = red[8] + red[9] + red[10] + red[11];
  const float Q2 = red[12] + red[13] + red[14] + red[15];
  const float mean1 = S1 * (1.0f / 4096.0f);
  const float rstd1 = rsqrtf(Q1 * (1.0f / 4096.0f) - mean1 * mean1 + 1e-5f);
  const float mean2 = S2 * (1.0f / 1024.0f);
  const float rstd2 = rsqrtf(Q2 * (1.0f / 1024.0f) - mean2 * mean2 + 1e-5f);

  // normalize + bounce through freed LDS
  unsigned short* ob1 = adjb;
  unsigned short* ob2 = Z1T;
  #pragma unroll
  for (int j = 0; j < 4; ++j) {
    const int k = 16 * j + l15;
    #pragma unroll
    for (int r = 0; r < 4; ++r) {
      const int m = 16 * wv + 4 * q + r;
      const int pos = m * 64 + k;
      float vv2 = (acc2[j][r] - mean1) * rstd1 * ln1g[pos] + ln1b[pos];
      ob1[pos] = f2bf(vv2);
    }
  }
  {
    const int f = l15;
    #pragma unroll
    for (int r = 0; r < 4; ++r) {
      const int m = 16 * wv + 4 * q + r;
      const int pos = m * 16 + f;
      float vv2 = (acc3[r] - mean2) * rstd2 * ln2g[pos] + ln2b[pos];
      ob2[pos] = f2bf(vv2);
    }
  }
  __syncthreads();
  {
    const uint4* sp = reinterpret_cast<const uint4*>(ob1);
    uint4* dp = reinterpret_cast<uint4*>(lnadj + (size_t)b * 4096);
    for (int i = tid; i < 512; i += 256) dp[i] = sp[i];
    if (tid < 128)
      reinterpret_cast<uint4*>(lnfeats + (size_t)b * 1024)[tid] =
          reinterpret_cast<const uint4*>(ob2)[tid];
  }
}

// ---------------------------------------------------------------------------
// TAIL kernel (R21): fc4 + fc5 GEMMs; W now pre-converted bf16 (from fused
// converter blocks) -> staging is a pure uint4 copy (half bytes, no VALU
// conversion). grid (32, 8).
// ---------------------------------------------------------------------------
#define GP 72
__launch_bounds__(256, 2)
__global__ void tail_kernel(const unsigned short* __restrict__ lnadj,
                            const unsigned short* __restrict__ w4b,
                            const float* __restrict__ fc4b,
                            const unsigned short* __restrict__ lnfeats,
                            const unsigned short* __restrict__ w5b,
                            const float* __restrict__ fc5b,
                            float* __restrict__ h45)
{
  const int tid = threadIdx.x;
  const int by = blockIdx.y;

  __shared__ __align__(16) unsigned short At[64 * GP];
  __shared__ __align__(16) unsigned short Wt[64 * GP];
  const bool is4 = (by < 4);
  const unsigned short* A = is4 ? lnadj : lnfeats;
  const unsigned short* W = is4 ? w4b : w5b;
  const float* bias = is4 ? fc4b : fc5b;
  const int K = is4 ? 4096 : 1024;
  const int coff = is4 ? 0 : 256;
  const int m0 = blockIdx.x * 64;
  const int n0 = (is4 ? by : (by - 4)) * 64;
  const int w = tid >> 6, lane = tid & 63;
  const int l15 = lane & 15, q = lane >> 4;
  const int srow = tid >> 2, sko = (tid & 3) * 16;

  f32x4 acc[4];
  #pragma unroll
  for (int j = 0; j < 4; ++j) acc[j] = f32x4{0.f, 0.f, 0.f, 0.f};

  for (int kc = 0; kc < K; kc += 64) {
    __syncthreads();
    {
      const unsigned short* ap = &A[(size_t)(m0 + srow) * K + kc + sko];
      *reinterpret_cast<uint4*>(&At[srow * GP + sko]) =
          *reinterpret_cast<const uint4*>(ap);
      *reinterpret_cast<uint4*>(&At[srow * GP + sko + 8]) =
          *reinterpret_cast<const uint4*>(ap + 8);
      const unsigned short* wp = &W[(size_t)(n0 + srow) * K + kc + sko];
      *reinterpret_cast<uint4*>(&Wt[srow * GP + sko]) =
          *reinterpret_cast<const uint4*>(wp);
      *reinterpret_cast<uint4*>(&Wt[srow * GP + sko + 8]) =
          *reinterpret_cast<const uint4*>(wp + 8);
    }
    __syncthreads();
    #pragma unroll
    for (int s = 0; s < 2; ++s) {
      bf16x8 af = ldfrag(&At[(16 * w + l15) * GP + 32 * s + 8 * q]);
      #pragma unroll
      for (int j = 0; j < 4; ++j) {
        bf16x8 bf = ldfrag(&Wt[(16 * j + l15) * GP + 32 * s + 8 * q]);
        acc[j] = __builtin_amdgcn_mfma_f32_16x16x32_bf16(af, bf, acc[j], 0, 0, 0);
      }
    }
  }
  #pragma unroll
  for (int j = 0; j < 4; ++j) {
    const int col = n0 + 16 * j + l15;
    const float bb = bias[col];
    #pragma unroll
    for (int r = 0; r < 4; ++r) {
      const int m = m0 + 16 * w + 4 * q + r;
      h45[(size_t)m * 512 + coff + col] = fmaxf(acc[j][r] + bb, 0.0f);
    }
  }
}

// ---------------------------------------------------------------------------
// Kernel D: unchanged (8 rows/block).
// ---------------------------------------------------------------------------
__launch_bounds__(256)
__global__ void head_kernel(const float* __restrict__ h45,
                            const float* __restrict__ wT6,   // [512][64]
                            const float* __restrict__ b6,
                            const float* __restrict__ w7,    // [10][64]
                            const float* __restrict__ b7,
                            float* __restrict__ out)
{
  __shared__ float row[8][512];
  __shared__ float h6[8][64];
  __shared__ float zb[8][12];
  const int tid = threadIdx.x;
  const int r0 = blockIdx.x * 8;
  for (int i = tid; i < 8 * 128; i += 256) {
    int r = i >> 7, c4 = i & 127;
    *reinterpret_cast<float4*>(&row[r][c4 * 4]) =
        reinterpret_cast<const float4*>(h45 + (size_t)(r0 + r) * 512)[c4];
  }
  __syncthreads();
  const int o = tid & 63, rg = tid >> 6;
  float a0 = b6[o], a1 = a0;
  #pragma unroll 8
  for (int k = 0; k < 512; ++k) {
    float wv = wT6[k * 64 + o];
    a0 += row[rg][k] * wv;
    a1 += row[rg + 4][k] * wv;
  }
  h6[rg][o] = fmaxf(a0, 0.0f);
  h6[rg + 4][o] = fmaxf(a1, 0.0f);
  __syncthreads();
  if (tid < 80) {
    int r = tid / 10, c = tid - r * 10;
    float z = b7[c];
    #pragma unroll
    for (int k = 0; k < 64; ++k) z += h6[r][k] * w7[c * 64 + k];
    zb[r][c] = z;
  }
  __syncthreads();
  if (tid < 80) {
    int r = tid / 10, c = tid - r * 10;
    float mx = zb[r][0];
    #pragma unroll
    for (int j = 1; j < 10; ++j) mx = fmaxf(mx, zb[r][j]);
    float se = 0.f;
    #pragma unroll
    for (int j = 0; j < 10; ++j) se += __expf(zb[r][j] - mx);
    out[(size_t)(r0 + r) * 10 + c] = zb[r][c] - mx - __logf(se);
  }
}

// ---------------------------------------------------------------------------
extern "C" void kernel_launch(void* const* d_in, const int* in_sizes, int n_in,
                              void* d_out, int out_size, void* d_ws, size_t ws_size,
                              hipStream_t stream)
{
  (void)in_sizes; (void)n_in; (void)out_size; (void)ws_size;
  const float* x    = (const float*)d_in[0];
  const float* adj  = (const float*)d_in[1];
  const float* w1   = (const float*)d_in[2];
  const float* w2   = (const float*)d_in[3];
  const float* alpha = (const float*)d_in[4];
  const float* bin_score = (const float*)d_in[5];
  const float* fc2w = (const float*)d_in[6];
  const float* fc2b = (const float*)d_in[7];
  const float* fc3w = (const float*)d_in[8];
  const float* fc3b = (const float*)d_in[9];
  const float* ln1g = (const float*)d_in[10];
  const float* ln1b = (const float*)d_in[11];
  const float* fc4w = (const float*)d_in[12];
  const float* fc4b = (const float*)d_in[13];
  const float* ln2g = (const float*)d_in[14];
  const float* ln2b = (const float*)d_in[15];
  const float* fc5w = (const float*)d_in[16];
  const float* fc5b = (const float*)d_in[17];
  const float* fc6w = (const float*)d_in[18];
  const float* fc6b = (const float*)d_in[19];
  const float* fc7w = (const float*)d_in[20];
  const float* fc7b = (const float*)d_in[21];
  float* out = (float*)d_out;

  char* ws = (char*)d_ws;
  size_t off = 0;
  unsigned short* lnadj = (unsigned short*)(ws + off);  off += (size_t)2048 * 4096 * 2;
  unsigned short* lnfeats = (unsigned short*)(ws + off); off += (size_t)2048 * 1024 * 2;
  float* h45 = (float*)(ws + off);                      off += (size_t)2048 * 512 * 4;
  float* wT6 = (float*)(ws + off);                      off += (size_t)512 * 64 * 4;
  unsigned short* w4b = (unsigned short*)(ws + off);    off += (size_t)256 * 4096 * 2;
  unsigned short* w5b = (unsigned short*)(ws + off);    off += (size_t)256 * 1024 * 2;

  hipLaunchKernelGGL(fused_kernel, dim3(2056), dim3(256), 0, stream,
                     x, adj, w1, w2, alpha, bin_score,
                     fc2w, fc2b, fc3w, fc3b,
                     ln1g, ln1b, ln2g, ln2b,
                     fc4w, fc5w, fc6w, w4b, w5b, wT6,
                     lnadj, lnfeats);
  hipLaunchKernelGGL(tail_kernel, dim3(32, 8), dim3(256), 0, stream,
                     lnadj, w4b, fc4b, lnfeats, w5b, fc5b, h45);
  hipLaunchKernelGGL(head_kernel, dim3(256), dim3(256), 0, stream,
                     h45, wT6, fc6b, fc7w, fc7b, out);
}

// Round 22
// 171.231 us; speedup vs baseline: 1.3348x; 1.0842x over previous
//
#include <hip/hip_runtime.h>
#include <hip/hip_bf16.h>
#include <hip/hip_fp16.h>

// Problem constants
#define B_   2048
#define NN   128    // NMAX
#define MM   64     // HN
#define HD_  128
#define IND  18
#define FD_  16
#define NCONV 32    // converter blocks at the FRONT of the fused grid

typedef unsigned int u32;
typedef _Float16 h2_t __attribute__((ext_vector_type(2)));
typedef __attribute__((ext_vector_type(8))) short bf16x8;
typedef __attribute__((ext_vector_type(4))) float f32x4;

__device__ __forceinline__ float fdot2f(u32 a, u32 b, float c) {
#if defined(__has_builtin)
#if __has_builtin(__builtin_amdgcn_fdot2)
  return __builtin_amdgcn_fdot2(__builtin_bit_cast(h2_t, a),
                                __builtin_bit_cast(h2_t, b), c, false);
#else
  h2_t x = __builtin_bit_cast(h2_t, a), y = __builtin_bit_cast(h2_t, b);
  return c + (float)x[0] * (float)y[0] + (float)x[1] * (float)y[1];
#endif
#else
  h2_t x = __builtin_bit_cast(h2_t, a), y = __builtin_bit_cast(h2_t, b);
  return c + (float)x[0] * (float)y[0] + (float)x[1] * (float)y[1];
#endif
}

__device__ __forceinline__ u32 pk2(float a, float b) {
#if defined(__has_builtin)
#if __has_builtin(__builtin_amdgcn_cvt_pkrtz)
  return __builtin_bit_cast(u32, __builtin_amdgcn_cvt_pkrtz(a, b));
#else
  __half ha = __float2half_rn(a), hb = __float2half_rn(b);
  return (u32)__half_as_ushort(ha) | ((u32)__half_as_ushort(hb) << 16);
#endif
#else
  __half ha = __float2half_rn(a), hb = __float2half_rn(b);
  return (u32)__half_as_ushort(ha) | ((u32)__half_as_ushort(hb) << 16);
#endif
}

__device__ __forceinline__ float rcpf_(float x) {
#if defined(__has_builtin)
#if __has_builtin(__builtin_amdgcn_rcpf)
  return __builtin_amdgcn_rcpf(x);
#else
  return 1.0f / x;
#endif
#else
  return 1.0f / x;
#endif
}

__device__ __forceinline__ float h_lo(u32 d) {
  return __half2float(__ushort_as_half((unsigned short)(d & 0xffffu)));
}
__device__ __forceinline__ float h_hi(u32 d) {
  return __half2float(__ushort_as_half((unsigned short)(d >> 16)));
}

__device__ __forceinline__ float bf2f(unsigned short u) {
  union { float f; u32 i; } z; z.i = ((u32)u) << 16; return z.f;
}
__device__ __forceinline__ unsigned short f2bf(float f) {
  union { float fv; u32 u; } z; z.fv = f;
  u32 lsb = (z.u >> 16) & 1u;
  return (unsigned short)((z.u + 0x7fffu + lsb) >> 16);
}
__device__ __forceinline__ u32 bfpk(float a, float b) {
  return (u32)f2bf(a) | ((u32)f2bf(b) << 16);
}
__device__ __forceinline__ bf16x8 ldfrag(const unsigned short* p) {
  return __builtin_bit_cast(bf16x8, *reinterpret_cast<const uint4*>(p));
}
__device__ __forceinline__ u32 comb2(u32 ps, u32 pf, float a, float na) {
  float r0 = a * bf2f((unsigned short)(ps & 0xffffu)) + na * bf2f((unsigned short)(pf & 0xffffu));
  float r1 = a * bf2f((unsigned short)(ps >> 16)) + na * bf2f((unsigned short)(pf >> 16));
  return (u32)f2bf(r0) | ((u32)f2bf(r1) << 16);
}

// ---------------------------------------------------------------------------
// FUSED kernel (R22 = R21 with converter blocks MOVED TO THE FRONT of the
// grid, spread over 32 blocks). R21's appended converters ran as stragglers
// in the last scheduling round (+30us dispatch tail); front placement runs
// them in round 1 concurrently with 736 batch blocks (~10us, hidden).
// Blocks 0..31: convert fc4w/fc5w f32->bf16 + fc6 transpose, return.
// Blocks 32..2079: batch b-32, R20's validated OT+align (84 VGPR, 53KB LDS).
// ---------------------------------------------------------------------------
#define AP 136   // bf16 row pitch (272 B); 68 dwords

__launch_bounds__(256, 3)
__global__ void fused_kernel(const float* __restrict__ x,
                             const float* __restrict__ adj,
                             const float* __restrict__ w1,
                             const float* __restrict__ w2,
                             const float* __restrict__ alpha_p,
                             const float* __restrict__ bin_score,
                             const float* __restrict__ fc2w, const float* __restrict__ fc2b,
                             const float* __restrict__ fc3w, const float* __restrict__ fc3b,
                             const float* __restrict__ ln1g, const float* __restrict__ ln1b,
                             const float* __restrict__ ln2g, const float* __restrict__ ln2b,
                             const float* __restrict__ fc4w_g,
                             const float* __restrict__ fc5w_g,
                             const float* __restrict__ fc6w_g,
                             unsigned short* __restrict__ w4b,
                             unsigned short* __restrict__ w5b,
                             float* __restrict__ wT6,
                             unsigned short* __restrict__ lnadj,
                             unsigned short* __restrict__ lnfeats)
{
  const int tid = threadIdx.x;

  if (blockIdx.x < NCONV) {
    // -------- converter blocks (front of grid; no LDS, no barriers) --------
    const int ct = blockIdx.x * 256 + tid;   // 0..8191
    {
      const float4* s4 = reinterpret_cast<const float4*>(fc4w_g);
      uint2* d4 = reinterpret_cast<uint2*>(w4b);
      for (int i = ct; i < 256 * 4096 / 4; i += NCONV * 256) {
        float4 v = s4[i];
        d4[i] = make_uint2(bfpk(v.x, v.y), bfpk(v.z, v.w));
      }
    }
    {
      const float4* s5 = reinterpret_cast<const float4*>(fc5w_g);
      uint2* d5 = reinterpret_cast<uint2*>(w5b);
      for (int i = ct; i < 256 * 1024 / 4; i += NCONV * 256) {
        float4 v = s5[i];
        d5[i] = make_uint2(bfpk(v.x, v.y), bfpk(v.z, v.w));
      }
    }
    for (int i = ct; i < 64 * 512; i += NCONV * 256) {
      int rr = i >> 9, cc = i & 511;
      wT6[cc * 64 + rr] = fc6w_g[i];
    }
    return;
  }

  const int b = blockIdx.x - NCONV;

  __shared__ __align__(16) u32 Ksh[64 * 68];               // 17408 B: K0 -> P0 -> Pc
  __shared__ __align__(16) u32 vhs[2][64];
  __shared__ __align__(16) u32 uhs[2][32];
  __shared__ __align__(16) unsigned short adjb[64 * AP];   // actw / adj halves / xfT / ob1
  __shared__ __align__(16) unsigned short Z1T[64 * AP];    // K1 -> P1 -> Z1 -> ob2
  __shared__ float red[16];

  const int wv = tid >> 6;
  const int lane = tid & 63;
  const int l15 = lane & 15, q = lane >> 4;
  u32* K1u = reinterpret_cast<u32*>(Z1T);

  // ======================= Phase A: scores -> K ==========================
  {
    const int sw = wv & 1;               // stream
    const int mtbase = (wv >> 1) * 4;    // slice half
    const float* wm = sw ? w2 : w1;
    const float* fw = sw ? fc3w : fc2w;
    const float* fb = sw ? fc3b : fc2b;
    unsigned short* Kshh = sw ? Z1T : reinterpret_cast<unsigned short*>(Ksh);
    unsigned short* actw = adjb + (size_t)wv * (16 * AP);  // per-wave scratch

    uint4 fcwB[8];
    #pragma unroll
    for (int nt = 0; nt < 8; ++nt) {
      const int ch = 16 * nt + l15;
      uint4 o = make_uint4(0u, 0u, 0u, 0u);
      if (sw) {
        if (q < 2) {
          const float* fr = fw + (size_t)ch * 16 + 8 * q;
          float4 va = *reinterpret_cast<const float4*>(fr);
          float4 vb = *reinterpret_cast<const float4*>(fr + 4);
          o = make_uint4(bfpk(va.x, va.y), bfpk(va.z, va.w),
                         bfpk(vb.x, vb.y), bfpk(vb.z, vb.w));
        }
      } else {
        if (q == 0) o.x = bfpk(fw[ch * 2], fw[ch * 2 + 1]);
      }
      fcwB[nt] = o;
    }
    float bb[8];
    #pragma unroll
    for (int nt = 0; nt < 8; ++nt) bb[nt] = fb[16 * nt + l15];

    #pragma unroll 1
    for (int mi = 0; mi < 4; ++mi) {
      const int mt = mtbase + mi;
      uint4 xv = make_uint4(0u, 0u, 0u, 0u);
      {
        const int node = 16 * mt + l15;
        const float* xp = x + ((size_t)b * NN + node) * IND + (sw ? 2 : 0);
        if (sw) {
          if (q < 2) {
            float2 p0 = *reinterpret_cast<const float2*>(xp + 8 * q);
            float2 p1 = *reinterpret_cast<const float2*>(xp + 8 * q + 2);
            float2 p2 = *reinterpret_cast<const float2*>(xp + 8 * q + 4);
            float2 p3 = *reinterpret_cast<const float2*>(xp + 8 * q + 6);
            xv = make_uint4(bfpk(p0.x, p0.y), bfpk(p1.x, p1.y),
                            bfpk(p2.x, p2.y), bfpk(p3.x, p3.y));
          }
        } else {
          if (q == 0) {
            float2 p0 = *reinterpret_cast<const float2*>(xp);
            xv.x = bfpk(p0.x, p0.y);
          }
        }
      }
      #pragma unroll
      for (int hh = 0; hh < 2; ++hh) {
        f32x4 a4[4];
        #pragma unroll
        for (int nt = 0; nt < 4; ++nt)
          a4[nt] = __builtin_amdgcn_mfma_f32_16x16x32_bf16(
              __builtin_bit_cast(bf16x8, xv),
              __builtin_bit_cast(bf16x8, fcwB[4 * hh + nt]),
              f32x4{0.f, 0.f, 0.f, 0.f}, 0, 0, 0);
        #pragma unroll
        for (int nt = 0; nt < 4; ++nt) {
          const int ntg = 4 * hh + nt;
          #pragma unroll
          for (int r = 0; r < 4; ++r) {
            float v = fmaxf(a4[nt][r] + bb[ntg], 0.0f);
            actw[(4 * q + r) * AP + 16 * ntg + l15] = f2bf(v);
          }
        }
      }
      uint4 sB[4];
      #pragma unroll
      for (int kt = 0; kt < 4; ++kt)
        sB[kt] = *reinterpret_cast<const uint4*>(&actw[l15 * AP + 32 * kt + 8 * q]);
      #pragma unroll
      for (int at = 0; at < 4; ++at) {
        const float* wrow = wm + (size_t)(16 * at + l15) * 128;
        f32x4 sa = f32x4{0.f, 0.f, 0.f, 0.f};
        #pragma unroll
        for (int kt = 0; kt < 4; ++kt) {
          float4 va = *reinterpret_cast<const float4*>(wrow + 32 * kt + 8 * q);
          float4 vb = *reinterpret_cast<const float4*>(wrow + 32 * kt + 8 * q + 4);
          uint4 wf = make_uint4(bfpk(va.x, va.y), bfpk(va.z, va.w),
                                bfpk(vb.x, vb.y), bfpk(vb.z, vb.w));
          sa = __builtin_amdgcn_mfma_f32_16x16x32_bf16(
              __builtin_bit_cast(bf16x8, wf), __builtin_bit_cast(bf16x8, sB[kt]),
              sa, 0, 0, 0);
        }
        #pragma unroll
        for (int r = 0; r < 4; ++r) {
          float kv = fminf(__expf(fmaxf(sa[r], 0.0f)), 60000.0f);
          Kshh[(16 * at + 4 * q + r) * AP + 16 * mt + l15] =
              __half_as_ushort(__float2half_rn(kv));
        }
      }
    }
  }
  __syncthreads();   // K0 (Ksh), K1 (Z1T) complete; actw (adjb) dead

  const float ebs = __expf(bin_score[0]);

  // ============== Phase B: Sinkhorn (waves 0-1) | adj h0 (waves 2-3) =====
  if (wv < 2) {
    const int l = lane;
    u32* Ks = (wv == 0) ? Ksh : K1u;
    u32 kr[64];
    #pragma unroll
    for (int t = 0; t < 16; ++t) {
      uint4 kv = *reinterpret_cast<const uint4*>(Ks + l * 68 + 4 * t);
      kr[4 * t + 0] = kv.x; kr[4 * t + 1] = kv.y;
      kr[4 * t + 2] = kv.z; kr[4 * t + 3] = kv.w;
    }

    u32* vh = vhs[wv];
    u32* uh = uhs[wv];
    vh[l] = 0x3C003C00u;
    float v128 = 1.0f, sum_v = 129.0f;
    float u_old = 0.0f, vo0 = 1.0f, vo1 = 1.0f;
    float ur = 0.0f;
    const float TOL = 1.5e-3f;

    for (int it = 0; it < 100; ++it) {
      const float u64v = 128.0f * rcpf_(ebs * sum_v);
      float a0 = ebs * v128, a1 = 0.f, a2 = 0.f, a3 = 0.f;
      const uint4* vh4 = reinterpret_cast<const uint4*>(vh);
      #pragma unroll
      for (int t = 0; t < 16; ++t) {
        uint4 vvv = vh4[t];
        a0 = fdot2f(kr[4 * t + 0], vvv.x, a0);
        a1 = fdot2f(kr[4 * t + 1], vvv.y, a1);
        a2 = fdot2f(kr[4 * t + 2], vvv.z, a2);
        a3 = fdot2f(kr[4 * t + 3], vvv.w, a3);
      }
      float urn = rcpf_((a0 + a1) + (a2 + a3));
      float m1 = fabsf(urn - u_old) - TOL * urn;
      u_old = urn; ur = urn;
      float su = urn;
      su += __shfl_xor(su, 1);  su += __shfl_xor(su, 2);
      su += __shfl_xor(su, 4);  su += __shfl_xor(su, 8);
      su += __shfl_xor(su, 16); su += __shfl_xor(su, 32);
      const float sum_u = su + u64v;
      const float v128n = 64.0f * rcpf_(ebs * sum_u);
      float upr = __shfl_xor(urn, 1);
      if (!(l & 1)) uh[l >> 1] = pk2(urn, upr);
      float c0a = ebs * u64v, c0b = 0.f, c1a = ebs * u64v, c1b = 0.f;
      #pragma unroll
      for (int j = 0; j < 32; ++j) {
        u32 d0 = Ks[(2 * j) * 68 + l];
        u32 d1 = Ks[(2 * j + 1) * 68 + l];
        u32 ka = (d0 & 0xffffu) | (d1 << 16);
        u32 kb = (d0 >> 16) | (d1 & 0xffff0000u);
        u32 uw = uh[j];
        if (j & 1) { c0b = fdot2f(ka, uw, c0b); c1b = fdot2f(kb, uw, c1b); }
        else       { c0a = fdot2f(ka, uw, c0a); c1a = fdot2f(kb, uw, c1a); }
      }
      float v0n = rcpf_(c0a + c0b);
      float v1n = rcpf_(c1a + c1b);
      float m2 = fabsf(v0n - vo0) - TOL * v0n;
      float m3 = fabsf(v1n - vo1) - TOL * v1n;
      vo0 = v0n; vo1 = v1n;
      vh[l] = pk2(v0n, v1n);
      float sv = v0n + v1n;
      sv += __shfl_xor(sv, 1);  sv += __shfl_xor(sv, 2);
      sv += __shfl_xor(sv, 4);  sv += __shfl_xor(sv, 8);
      sv += __shfl_xor(sv, 16); sv += __shfl_xor(sv, 32);
      sum_v = sv + v128n;
      v128 = v128n;
      float mcond = fmaxf(m1, fmaxf(m2, m3));
      if (__all(mcond <= 0.0f)) break;
    }

    // P = K*u*v (bf16) IN PLACE over Ks
    {
      const uint4* vh4 = reinterpret_cast<const uint4*>(vh);
      #pragma unroll
      for (int t = 0; t < 16; ++t) {
        uint4 vvv = vh4[t];
        u32 o0 = bfpk(h_lo(kr[4 * t + 0]) * ur * h_lo(vvv.x),
                      h_hi(kr[4 * t + 0]) * ur * h_hi(vvv.x));
        u32 o1 = bfpk(h_lo(kr[4 * t + 1]) * ur * h_lo(vvv.y),
                      h_hi(kr[4 * t + 1]) * ur * h_hi(vvv.y));
        u32 o2 = bfpk(h_lo(kr[4 * t + 2]) * ur * h_lo(vvv.z),
                      h_hi(kr[4 * t + 2]) * ur * h_hi(vvv.z));
        u32 o3 = bfpk(h_lo(kr[4 * t + 3]) * ur * h_lo(vvv.w),
                      h_hi(kr[4 * t + 3]) * ur * h_hi(vvv.w));
        *reinterpret_cast<uint4*>(&Ks[l * 68 + 4 * t]) = make_uint4(o0, o1, o2, o3);
      }
    }
  } else {
    // stage adj rows 0..63 -> adjb (128 threads)
    const float4* src = reinterpret_cast<const float4*>(adj + (size_t)b * (NN * NN));
    for (int i = tid - 128; i < 64 * 32; i += 128) {
      int row = i >> 5, c4 = i & 31;
      float4 v = src[i];
      u32 w0 = (u32)f2bf(v.x) | ((u32)f2bf(v.y) << 16);
      u32 w1 = (u32)f2bf(v.z) | ((u32)f2bf(v.w) << 16);
      *reinterpret_cast<uint2*>(&adjb[row * AP + c4 * 4]) = make_uint2(w0, w1);
    }
  }
  __syncthreads();   // P0 (Ksh), P1 (Z1T); adjb h0 staged

  // ======================= Phase C: align ================================
  const float aa = 1.0f / (1.0f + __expf(-alpha_p[0]));
  const float na = 1.0f - aa;
  for (int i = tid; i < 4096; i += 256) {
    int row = i >> 6, cd = i & 63;
    Ksh[row * 68 + cd] = comb2(Ksh[row * 68 + cd], K1u[row * 68 + cd], aa, na);
  }
  __syncthreads();   // Pc ready; P1 (Z1T) dead
  const unsigned short* Pc = reinterpret_cast<const unsigned short*>(Ksh);

  // M1 half 0
  {
    f32x4 acch[4];
    #pragma unroll
    for (int j = 0; j < 4; ++j) acch[j] = f32x4{0.f, 0.f, 0.f, 0.f};
    #pragma unroll
    for (int kt = 0; kt < 4; ++kt) {
      const int d0 = 32 * kt + 8 * q;
      bf16x8 af = ldfrag(&adjb[(16 * wv + l15) * AP + d0]);
      #pragma unroll
      for (int j = 0; j < 4; ++j) {
        bf16x8 bf = ldfrag(&Pc[(16 * j + l15) * AP + d0]);
        acch[j] = __builtin_amdgcn_mfma_f32_16x16x32_bf16(af, bf, acch[j], 0, 0, 0);
      }
    }
    __syncthreads();
    #pragma unroll
    for (int j = 0; j < 4; ++j) {
      const int k = 16 * j + l15;
      const int nbase = 16 * wv + 4 * q;
      u32 w0 = (u32)f2bf(acch[j][0]) | ((u32)f2bf(acch[j][1]) << 16);
      u32 w1 = (u32)f2bf(acch[j][2]) | ((u32)f2bf(acch[j][3]) << 16);
      *reinterpret_cast<uint2*>(&Z1T[k * AP + nbase]) = make_uint2(w0, w1);
    }
  }
  __syncthreads();   // adjb h0 reads done

  // stage adj rows 64..127
  {
    const float4* src = reinterpret_cast<const float4*>(
        adj + (size_t)b * (NN * NN) + (size_t)64 * NN);
    for (int i = tid; i < 64 * 32; i += 256) {
      int row = i >> 5, c4 = i & 31;
      float4 v = src[i];
      u32 w0 = (u32)f2bf(v.x) | ((u32)f2bf(v.y) << 16);
      u32 w1 = (u32)f2bf(v.z) | ((u32)f2bf(v.w) << 16);
      *reinterpret_cast<uint2*>(&adjb[row * AP + c4 * 4]) = make_uint2(w0, w1);
    }
  }
  __syncthreads();

  // M1 half 1
  {
    f32x4 acch[4];
    #pragma unroll
    for (int j = 0; j < 4; ++j) acch[j] = f32x4{0.f, 0.f, 0.f, 0.f};
    #pragma unroll
    for (int kt = 0; kt < 4; ++kt) {
      const int d0 = 32 * kt + 8 * q;
      bf16x8 af = ldfrag(&adjb[(16 * wv + l15) * AP + d0]);
      #pragma unroll
      for (int j = 0; j < 4; ++j) {
        bf16x8 bf = ldfrag(&Pc[(16 * j + l15) * AP + d0]);
        acch[j] = __builtin_amdgcn_mfma_f32_16x16x32_bf16(af, bf, acch[j], 0, 0, 0);
      }
    }
    #pragma unroll
    for (int j = 0; j < 4; ++j) {
      const int k = 16 * j + l15;
      const int nbase = 64 + 16 * wv + 4 * q;
      u32 w0 = (u32)f2bf(acch[j][0]) | ((u32)f2bf(acch[j][1]) << 16);
      u32 w1 = (u32)f2bf(acch[j][2]) | ((u32)f2bf(acch[j][3]) << 16);
      *reinterpret_cast<uint2*>(&Z1T[k * AP + nbase]) = make_uint2(w0, w1);
    }
  }
  __syncthreads();   // Z1T complete; adjb free

  // stage xfT into adjb tail
  unsigned short* xfT = adjb + 48 * AP;
  for (int i = tid; i < 2048; i += 256) {
    int n = i & 127, f = i >> 7;
    xfT[f * AP + n] = f2bf(x[((size_t)b * NN + n) * IND + 2 + f]);
  }
  __syncthreads();

  // M2: al2 = Pc @ Z1 ; M3: feats = Pc @ xf
  f32x4 acc2[4];
  f32x4 acc3 = f32x4{0.f, 0.f, 0.f, 0.f};
  #pragma unroll
  for (int j = 0; j < 4; ++j) acc2[j] = f32x4{0.f, 0.f, 0.f, 0.f};
  #pragma unroll
  for (int nt = 0; nt < 4; ++nt) {
    const int n0 = 32 * nt + 8 * q;
    bf16x8 af = ldfrag(&Pc[(16 * wv + l15) * AP + n0]);
    #pragma unroll
    for (int j = 0; j < 4; ++j) {
      bf16x8 bv = ldfrag(&Z1T[(16 * j + l15) * AP + n0]);
      acc2[j] = __builtin_amdgcn_mfma_f32_16x16x32_bf16(af, bv, acc2[j], 0, 0, 0);
    }
    bf16x8 bx = ldfrag(&xfT[l15 * AP + n0]);
    acc3 = __builtin_amdgcn_mfma_f32_16x16x32_bf16(af, bx, acc3, 0, 0, 0);
  }

  // LN reductions
  {
    float s1 = 0.f, q1 = 0.f, s2 = 0.f, q2 = 0.f;
    #pragma unroll
    for (int j = 0; j < 4; ++j)
      #pragma unroll
      for (int r = 0; r < 4; ++r) { float v = acc2[j][r]; s1 += v; q1 += v * v; }
    #pragma unroll
    for (int r = 0; r < 4; ++r) { float v = acc3[r]; s2 += v; q2 += v * v; }
    #pragma unroll
    for (int off = 1; off < 64; off <<= 1) {
      s1 += __shfl_xor(s1, off); q1 += __shfl_xor(q1, off);
      s2 += __shfl_xor(s2, off); q2 += __shfl_xor(q2, off);
    }
    if (lane == 0) { red[wv] = s1; red[4 + wv] = q1; red[8 + wv] = s2; red[12 + wv] = q2; }
  }
  __syncthreads();
  const float S1 = red[0] + red[1] + red[2] + red[3];
  const float Q1 = red[4] + red[5] + red[6] + red[7];
  const float S2 = red[8] + red[9] + red[10] + red[11];
  const float Q2 = red[12] + red[13] + red[14] + red[15];
  const float mean1 = S1 * (1.0f / 4096.0f);
  const float rstd1 = rsqrtf(Q1 * (1.0f / 4096.0f) - mean1 * mean1 + 1e-5f);
  const float mean2 = S2 * (1.0f / 1024.0f);
  const float rstd2 = rsqrtf(Q2 * (1.0f / 1024.0f) - mean2 * mean2 + 1e-5f);

  // normalize + bounce through freed LDS
  unsigned short* ob1 = adjb;
  unsigned short* ob2 = Z1T;
  #pragma unroll
  for (int j = 0; j < 4; ++j) {
    const int k = 16 * j + l15;
    #pragma unroll
    for (int r = 0; r < 4; ++r) {
      const int m = 16 * wv + 4 * q + r;
      const int pos = m * 64 + k;
      float vv2 = (acc2[j][r] - mean1) * rstd1 * ln1g[pos] + ln1b[pos];
      ob1[pos] = f2bf(vv2);
    }
  }
  {
    const int f = l15;
    #pragma unroll
    for (int r = 0; r < 4; ++r) {
      const int m = 16 * wv + 4 * q + r;
      const int pos = m * 16 + f;
      float vv2 = (acc3[r] - mean2) * rstd2 * ln2g[pos] + ln2b[pos];
      ob2[pos] = f2bf(vv2);
    }
  }
  __syncthreads();
  {
    const uint4* sp = reinterpret_cast<const uint4*>(ob1);
    uint4* dp = reinterpret_cast<uint4*>(lnadj + (size_t)b * 4096);
    for (int i = tid; i < 512; i += 256) dp[i] = sp[i];
    if (tid < 128)
      reinterpret_cast<uint4*>(lnfeats + (size_t)b * 1024)[tid] =
          reinterpret_cast<const uint4*>(ob2)[tid];
  }
}

// ---------------------------------------------------------------------------
// TAIL kernel (R21, unchanged): fc4 + fc5 GEMMs with pre-converted bf16 W.
// ---------------------------------------------------------------------------
#define GP 72
__launch_bounds__(256, 2)
__global__ void tail_kernel(const unsigned short* __restrict__ lnadj,
                            const unsigned short* __restrict__ w4b,
                            const float* __restrict__ fc4b,
                            const unsigned short* __restrict__ lnfeats,
                            const unsigned short* __restrict__ w5b,
                            const float* __restrict__ fc5b,
                            float* __restrict__ h45)
{
  const int tid = threadIdx.x;
  const int by = blockIdx.y;

  __shared__ __align__(16) unsigned short At[64 * GP];
  __shared__ __align__(16) unsigned short Wt[64 * GP];
  const bool is4 = (by < 4);
  const unsigned short* A = is4 ? lnadj : lnfeats;
  const unsigned short* W = is4 ? w4b : w5b;
  const float* bias = is4 ? fc4b : fc5b;
  const int K = is4 ? 4096 : 1024;
  const int coff = is4 ? 0 : 256;
  const int m0 = blockIdx.x * 64;
  const int n0 = (is4 ? by : (by - 4)) * 64;
  const int w = tid >> 6, lane = tid & 63;
  const int l15 = lane & 15, q = lane >> 4;
  const int srow = tid >> 2, sko = (tid & 3) * 16;

  f32x4 acc[4];
  #pragma unroll
  for (int j = 0; j < 4; ++j) acc[j] = f32x4{0.f, 0.f, 0.f, 0.f};

  for (int kc = 0; kc < K; kc += 64) {
    __syncthreads();
    {
      const unsigned short* ap = &A[(size_t)(m0 + srow) * K + kc + sko];
      *reinterpret_cast<uint4*>(&At[srow * GP + sko]) =
          *reinterpret_cast<const uint4*>(ap);
      *reinterpret_cast<uint4*>(&At[srow * GP + sko + 8]) =
          *reinterpret_cast<const uint4*>(ap + 8);
      const unsigned short* wp = &W[(size_t)(n0 + srow) * K + kc + sko];
      *reinterpret_cast<uint4*>(&Wt[srow * GP + sko]) =
          *reinterpret_cast<const uint4*>(wp);
      *reinterpret_cast<uint4*>(&Wt[srow * GP + sko + 8]) =
          *reinterpret_cast<const uint4*>(wp + 8);
    }
    __syncthreads();
    #pragma unroll
    for (int s = 0; s < 2; ++s) {
      bf16x8 af = ldfrag(&At[(16 * w + l15) * GP + 32 * s + 8 * q]);
      #pragma unroll
      for (int j = 0; j < 4; ++j) {
        bf16x8 bf = ldfrag(&Wt[(16 * j + l15) * GP + 32 * s + 8 * q]);
        acc[j] = __builtin_amdgcn_mfma_f32_16x16x32_bf16(af, bf, acc[j], 0, 0, 0);
      }
    }
  }
  #pragma unroll
  for (int j = 0; j < 4; ++j) {
    const int col = n0 + 16 * j + l15;
    const float bb = bias[col];
    #pragma unroll
    for (int r = 0; r < 4; ++r) {
      const int m = m0 + 16 * w + 4 * q + r;
      h45[(size_t)m * 512 + coff + col] = fmaxf(acc[j][r] + bb, 0.0f);
    }
  }
}

// ---------------------------------------------------------------------------
// Kernel D: unchanged (8 rows/block).
// ---------------------------------------------------------------------------
__launch_bounds__(256)
__global__ void head_kernel(const float* __restrict__ h45,
                            const float* __restrict__ wT6,   // [512][64]
                            const float* __restrict__ b6,
                            const float* __restrict__ w7,    // [10][64]
                            const float* __restrict__ b7,
                            float* __restrict__ out)
{
  __shared__ float row[8][512];
  __shared__ float h6[8][64];
  __shared__ float zb[8][12];
  const int tid = threadIdx.x;
  const int r0 = blockIdx.x * 8;
  for (int i = tid; i < 8 * 128; i += 256) {
    int r = i >> 7, c4 = i & 127;
    *reinterpret_cast<float4*>(&row[r][c4 * 4]) =
        reinterpret_cast<const float4*>(h45 + (size_t)(r0 + r) * 512)[c4];
  }
  __syncthreads();
  const int o = tid & 63, rg = tid >> 6;
  float a0 = b6[o], a1 = a0;
  #pragma unroll 8
  for (int k = 0; k < 512; ++k) {
    float wv = wT6[k * 64 + o];
    a0 += row[rg][k] * wv;
    a1 += row[rg + 4][k] * wv;
  }
  h6[rg][o] = fmaxf(a0, 0.0f);
  h6[rg + 4][o] = fmaxf(a1, 0.0f);
  __syncthreads();
  if (tid < 80) {
    int r = tid / 10, c = tid - r * 10;
    float z = b7[c];
    #pragma unroll
    for (int k = 0; k < 64; ++k) z += h6[r][k] * w7[c * 64 + k];
    zb[r][c] = z;
  }
  __syncthreads();
  if (tid < 80) {
    int r = tid / 10, c = tid - r * 10;
    float mx = zb[r][0];
    #pragma unroll
    for (int j = 1; j < 10; ++j) mx = fmaxf(mx, zb[r][j]);
    float se = 0.f;
    #pragma unroll
    for (int j = 0; j < 10; ++j) se += __expf(zb[r][j] - mx);
    out[(size_t)(r0 + r) * 10 + c] = zb[r][c] - mx - __logf(se);
  }
}

// ---------------------------------------------------------------------------
extern "C" void kernel_launch(void* const* d_in, const int* in_sizes, int n_in,
                              void* d_out, int out_size, void* d_ws, size_t ws_size,
                              hipStream_t stream)
{
  (void)in_sizes; (void)n_in; (void)out_size; (void)ws_size;
  const float* x    = (const float*)d_in[0];
  const float* adj  = (const float*)d_in[1];
  const float* w1   = (const float*)d_in[2];
  const float* w2   = (const float*)d_in[3];
  const float* alpha = (const float*)d_in[4];
  const float* bin_score = (const float*)d_in[5];
  const float* fc2w = (const float*)d_in[6];
  const float* fc2b = (const float*)d_in[7];
  const float* fc3w = (const float*)d_in[8];
  const float* fc3b = (const float*)d_in[9];
  const float* ln1g = (const float*)d_in[10];
  const float* ln1b = (const float*)d_in[11];
  const float* fc4w = (const float*)d_in[12];
  const float* fc4b = (const float*)d_in[13];
  const float* ln2g = (const float*)d_in[14];
  const float* ln2b = (const float*)d_in[15];
  const float* fc5w = (const float*)d_in[16];
  const float* fc5b = (const float*)d_in[17];
  const float* fc6w = (const float*)d_in[18];
  const float* fc6b = (const float*)d_in[19];
  const float* fc7w = (const float*)d_in[20];
  const float* fc7b = (const float*)d_in[21];
  float* out = (float*)d_out;

  char* ws = (char*)d_ws;
  size_t off = 0;
  unsigned short* lnadj = (unsigned short*)(ws + off);  off += (size_t)2048 * 4096 * 2;
  unsigned short* lnfeats = (unsigned short*)(ws + off); off += (size_t)2048 * 1024 * 2;
  float* h45 = (float*)(ws + off);                      off += (size_t)2048 * 512 * 4;
  float* wT6 = (float*)(ws + off);                      off += (size_t)512 * 64 * 4;
  unsigned short* w4b = (unsigned short*)(ws + off);    off += (size_t)256 * 4096 * 2;
  unsigned short* w5b = (unsigned short*)(ws + off);    off += (size_t)256 * 1024 * 2;

  hipLaunchKernelGGL(fused_kernel, dim3(B_ + NCONV), dim3(256), 0, stream,
                     x, adj, w1, w2, alpha, bin_score,
                     fc2w, fc2b, fc3w, fc3b,
                     ln1g, ln1b, ln2g, ln2b,
                     fc4w, fc5w, fc6w, w4b, w5b, wT6,
                     lnadj, lnfeats);
  hipLaunchKernelGGL(tail_kernel, dim3(32, 8), dim3(256), 0, stream,
                     lnadj, w4b, fc4b, lnfeats, w5b, fc5b, h45);
  hipLaunchKernelGGL(head_kernel, dim3(256), dim3(256), 0, stream,
                     h45, wT6, fc6b, fc7w, fc7b, out);
}